// Round 1
// baseline (2216.660 us; speedup 1.0000x reference)
//
#include <hip/hip_runtime.h>
#include <math.h>

#define B 4
#define C 128
#define H 64
#define W 64
#define G 8
#define CPG 16
#define INTER 32

__device__ __forceinline__ void scale_wts(const float* __restrict__ sw,
                                          float& w0, float& w1, float& w2) {
    float a = sw[0], b = sw[1], c = sw[2];
    float m = fmaxf(a, fmaxf(b, c));
    float e0 = __expf(a - m), e1 = __expf(b - m), e2 = __expf(c - m);
    float inv = 1.0f / (e0 + e1 + e2);
    w0 = e0 * inv; w1 = e1 * inv; w2 = e2 * inv;
}

// Average-pool x (B,C,64,64) -> xs (B,C,h,h), s = 64/h.
__global__ __launch_bounds__(256) void avgpool_kernel(const float* __restrict__ x,
                                                      float* __restrict__ xs,
                                                      int s, int h, int hShift) {
    int idx = blockIdx.x * 256 + threadIdx.x;
    int hw = h * h;
    int p = idx & (hw - 1);
    int bc = idx >> (2 * hShift);
    int oy = p >> hShift, ox = p & (h - 1);
    const float* src = x + (bc << 12) + (oy * s) * W + ox * s;
    float sum = 0.0f;
    for (int dy = 0; dy < s; ++dy)
        for (int dx = 0; dx < s; ++dx)
            sum += src[dy * W + dx];
    xs[idx] = sum * (1.0f / (s * s));
}

// GroupNorm statistics: one block per (b,g). Group channels are contiguous.
__global__ __launch_bounds__(256) void gn_stats_kernel(const float* __restrict__ xs,
                                                       float* __restrict__ stats,
                                                       int hw, int hwShift) {
    int bg = blockIdx.x;           // b*G + g
    int b = bg >> 3, g = bg & 7;
    int count = CPG * hw;
    const float* base = xs + ((b * C + g * CPG) << hwShift);
    float s = 0.0f, s2 = 0.0f;
    for (int i = threadIdx.x; i < count; i += 256) {
        float v = base[i];
        s += v; s2 += v * v;
    }
    __shared__ float rs[256], rs2[256];
    rs[threadIdx.x] = s; rs2[threadIdx.x] = s2;
    __syncthreads();
    for (int st = 128; st > 0; st >>= 1) {
        if (threadIdx.x < st) {
            rs[threadIdx.x] += rs[threadIdx.x + st];
            rs2[threadIdx.x] += rs2[threadIdx.x + st];
        }
        __syncthreads();
    }
    if (threadIdx.x == 0) {
        float inv = 1.0f / (float)count;
        float mu = rs[0] * inv;
        float var = rs2[0] * inv - mu * mu;
        stats[bg * 2] = mu;
        stats[bg * 2 + 1] = rsqrtf(var + 1e-5f);
    }
}

// xn = (xs - mu)*rsig*gn_w[c] + gn_b[c]
__global__ __launch_bounds__(256) void xn_kernel(const float* __restrict__ xs,
                                                 const float* __restrict__ stats,
                                                 const float* __restrict__ gn_w,
                                                 const float* __restrict__ gn_b,
                                                 float* __restrict__ xn, int hwShift) {
    int idx = blockIdx.x * 256 + threadIdx.x;
    int c = (idx >> hwShift) & (C - 1);
    int b = idx >> (hwShift + 7);
    int g = c >> 4;
    float mu = stats[(b * G + g) * 2];
    float rsig = stats[(b * G + g) * 2 + 1];
    xn[idx] = (xs[idx] - mu) * rsig * gn_w[c] + gn_b[c];
}

// q,k,v projections: qkv[proj][b][o][n] = sum_c w[o,c]*xn[b,c,n] + bias[o]
__global__ __launch_bounds__(256) void qkv_kernel(const float* __restrict__ xn,
                                                  const float* __restrict__ qw, const float* __restrict__ qb,
                                                  const float* __restrict__ kw, const float* __restrict__ kb,
                                                  const float* __restrict__ vw, const float* __restrict__ vb,
                                                  float* __restrict__ qkv, int N, int nShift) {
    int idx = blockIdx.x * 256 + threadIdx.x;
    int n = idx & (N - 1);
    int o = (idx >> nShift) & (INTER - 1);
    int b = (idx >> (nShift + 5)) & (B - 1);
    int proj = idx >> (nShift + 7);
    const float* wp = (proj == 0) ? qw : ((proj == 1) ? kw : vw);
    const float* bp = (proj == 0) ? qb : ((proj == 1) ? kb : vb);
    const float* xb = xn + ((b * C) << nShift);
    float acc = 0.0f;
    #pragma unroll 8
    for (int c0 = 0; c0 < C; ++c0)
        acc += wp[o * C + c0] * xb[(c0 << nShift) + n];
    qkv[idx] = acc + bp[o];
}

// Flash-style attention. One thread per query row. K/V tiles in LDS.
__global__ __launch_bounds__(256) void attn_kernel(const float* __restrict__ qkv,
                                                   float* __restrict__ att,
                                                   int N, int nShift, int nbShift) {
    int b = blockIdx.x >> nbShift;
    int qc = blockIdx.x & ((1 << nbShift) - 1);
    int n = qc * 256 + threadIdx.x;
    const float* q = qkv;
    const float* k = qkv + B * INTER * N;
    const float* v = qkv + 2 * B * INTER * N;
    const float invs = 0.17677669529663687f;  // 1/sqrt(32)

    float qv[INTER], acc[INTER];
    const float* qb_ = q + (b * INTER) * N + n;
    #pragma unroll
    for (int o = 0; o < INTER; ++o) { qv[o] = qb_[o << nShift] * invs; acc[o] = 0.0f; }
    float mrun = -3.0e38f, l = 0.0f;

    __shared__ float lk[INTER * 64], lv[INTER * 64];
    const float* kb_ = k + (b * INTER) * N;
    const float* vb_ = v + (b * INTER) * N;

    for (int m0 = 0; m0 < N; m0 += 64) {
        __syncthreads();
        #pragma unroll
        for (int r = 0; r < 8; ++r) {
            int e = r * 256 + threadIdx.x;     // e = o*64 + j
            int o = e >> 6, j = e & 63;
            lk[e] = kb_[(o << nShift) + m0 + j];
            lv[e] = vb_[(o << nShift) + m0 + j];
        }
        __syncthreads();
        for (int j = 0; j < 64; ++j) {
            float sc = 0.0f;
            #pragma unroll
            for (int o = 0; o < INTER; ++o) sc += qv[o] * lk[o * 64 + j];
            float nm = fmaxf(mrun, sc);
            float corr = __expf(mrun - nm);
            float p = __expf(sc - nm);
            l = l * corr + p;
            #pragma unroll
            for (int o = 0; o < INTER; ++o) acc[o] = acc[o] * corr + p * lv[o * 64 + j];
            mrun = nm;
        }
    }
    float invl = 1.0f / l;
    float* ab = att + (b * INTER) * N + n;
    #pragma unroll
    for (int o = 0; o < INTER; ++o) ab[o << nShift] = acc[o] * invl;
}

// o = ow@att + ob; y = gamma*o + xs. If sw != null: write w0*y (s=1 -> d_out).
__global__ __launch_bounds__(256) void oy_kernel(const float* __restrict__ att,
                                                 const float* __restrict__ ow,
                                                 const float* __restrict__ ob,
                                                 const float* __restrict__ gamma,
                                                 const float* __restrict__ xs,
                                                 float* __restrict__ ydst,
                                                 const float* __restrict__ sw,
                                                 int N, int nShift) {
    int idx = blockIdx.x * 256 + threadIdx.x;
    int n = idx & (N - 1);
    int c = (idx >> nShift) & (C - 1);
    int b = idx >> (nShift + 7);
    float acc = ob[c];
    const float* ab = att + ((b * INTER) << nShift) + n;
    #pragma unroll
    for (int i = 0; i < INTER; ++i) acc += ow[c * INTER + i] * ab[i << nShift];
    float y = gamma[0] * acc + xs[idx];
    if (sw) {
        float w0, w1, w2; scale_wts(sw, w0, w1, w2);
        ydst[idx] = w0 * y;
    } else {
        ydst[idx] = y;
    }
}

__device__ __forceinline__ float bilerp(const float* __restrict__ img, int in,
                                        int oy, int ox, float r) {
    float cy = (oy + 0.5f) * r - 0.5f;
    cy = fminf(fmaxf(cy, 0.0f), (float)(in - 1));
    float cx = (ox + 0.5f) * r - 0.5f;
    cx = fminf(fmaxf(cx, 0.0f), (float)(in - 1));
    int y0 = (int)cy; int y1i = (y0 + 1 < in) ? y0 + 1 : in - 1; float ty = cy - (float)y0;
    int x0 = (int)cx; int x1i = (x0 + 1 < in) ? x0 + 1 : in - 1; float tx = cx - (float)x0;
    float v00 = img[y0 * in + x0];
    float v01 = img[y0 * in + x1i];
    float v10 = img[y1i * in + x0];
    float v11 = img[y1i * in + x1i];
    float top = v00 * (1.0f - tx) + v01 * tx;
    float bot = v10 * (1.0f - tx) + v11 * tx;
    return top * (1.0f - ty) + bot * ty;
}

// out += w1*up(y2) + w2*up(y4)
__global__ __launch_bounds__(256) void fuse_kernel(float* __restrict__ out,
                                                   const float* __restrict__ y2,
                                                   const float* __restrict__ y4,
                                                   const float* __restrict__ sw) {
    int idx = blockIdx.x * 256 + threadIdx.x;    // B*C*4096
    int p = idx & 4095;
    int bc = idx >> 12;
    int oy = p >> 6, ox = p & 63;
    float w0, w1, w2; scale_wts(sw, w0, w1, w2);
    float v2 = bilerp(y2 + bc * 1024, 32, oy, ox, 0.5f);
    float v4 = bilerp(y4 + bc * 256, 16, oy, ox, 0.25f);
    out[idx] = out[idx] + w1 * v2 + w2 * v4;
}

extern "C" void kernel_launch(void* const* d_in, const int* in_sizes, int n_in,
                              void* d_out, int out_size, void* d_ws, size_t ws_size,
                              hipStream_t stream) {
    const float* x     = (const float*)d_in[0];
    const float* gn_w  = (const float*)d_in[1];
    const float* gn_b  = (const float*)d_in[2];
    const float* qw    = (const float*)d_in[3];
    const float* qb    = (const float*)d_in[4];
    const float* kw    = (const float*)d_in[5];
    const float* kb    = (const float*)d_in[6];
    const float* vw    = (const float*)d_in[7];
    const float* vb    = (const float*)d_in[8];
    const float* ow    = (const float*)d_in[9];
    const float* ob    = (const float*)d_in[10];
    const float* gamma = (const float*)d_in[11];
    const float* sw    = (const float*)d_in[12];
    float* out = (float*)d_out;

    float* ws    = (float*)d_ws;
    float* xs2   = ws;                                   // B*C*32*32 = 524288
    float* xs4   = xs2 + B * C * 32 * 32;                // B*C*16*16 = 131072
    float* xn    = xs4 + B * C * 16 * 16;                // B*C*64*64 = 2097152
    float* qkvb  = xn + B * C * 64 * 64;                 // 3*B*32*4096 = 1572864
    float* attb  = qkvb + 3 * B * INTER * 64 * 64;       // B*32*4096 = 524288
    float* y2    = attb + B * INTER * 64 * 64;           // 524288
    float* y4    = y2 + B * C * 32 * 32;                 // 131072
    float* stats = y4 + B * C * 16 * 16;                 // 64

    avgpool_kernel<<<B * C * 32 * 32 / 256, 256, 0, stream>>>(x, xs2, 2, 32, 5);
    avgpool_kernel<<<B * C * 16 * 16 / 256, 256, 0, stream>>>(x, xs4, 4, 16, 4);

    for (int i = 0; i < 3; ++i) {
        int hwShift = (i == 0) ? 12 : ((i == 1) ? 10 : 8);
        int hw = 1 << hwShift;
        const float* xsp = (i == 0) ? x : ((i == 1) ? xs2 : xs4);

        gn_stats_kernel<<<B * G, 256, 0, stream>>>(xsp, stats, hw, hwShift);
        xn_kernel<<<B * C * hw / 256, 256, 0, stream>>>(xsp, stats, gn_w + i * C, gn_b + i * C,
                                                        xn, hwShift);
        qkv_kernel<<<3 * B * INTER * hw / 256, 256, 0, stream>>>(
            xn, qw + i * INTER * C, qb + i * INTER,
            kw + i * INTER * C, kb + i * INTER,
            vw + i * INTER * C, vb + i * INTER, qkvb, hw, hwShift);
        attn_kernel<<<B * hw / 256, 256, 0, stream>>>(qkvb, attb, hw, hwShift, hwShift - 8);
        if (i == 0) {
            oy_kernel<<<B * C * hw / 256, 256, 0, stream>>>(
                attb, ow + i * C * INTER, ob + i * C, gamma + i, xsp, out, sw, hw, hwShift);
        } else {
            oy_kernel<<<B * C * hw / 256, 256, 0, stream>>>(
                attb, ow + i * C * INTER, ob + i * C, gamma + i, xsp,
                (i == 1) ? y2 : y4, nullptr, hw, hwShift);
        }
    }
    fuse_kernel<<<B * C * H * W / 256, 256, 0, stream>>>(out, y2, y4, sw);
}

// Round 2
// 454.295 us; speedup vs baseline: 4.8793x; 4.8793x over previous
//
#include <hip/hip_runtime.h>
#include <math.h>

#define B 4
#define C 128
#define H 64
#define W 64
#define G 8
#define CPG 16
#define INTER 32

__device__ __forceinline__ void scale_wts(const float* __restrict__ sw,
                                          float& w0, float& w1, float& w2) {
    float a = sw[0], b = sw[1], c = sw[2];
    float m = fmaxf(a, fmaxf(b, c));
    float e0 = __expf(a - m), e1 = __expf(b - m), e2 = __expf(c - m);
    float inv = 1.0f / (e0 + e1 + e2);
    w0 = e0 * inv; w1 = e1 * inv; w2 = e2 * inv;
}

// Average-pool x (B,C,64,64) -> xs (B,C,h,h), s = 64/h.
__global__ __launch_bounds__(256) void avgpool_kernel(const float* __restrict__ x,
                                                      float* __restrict__ xs,
                                                      int s, int h, int hShift) {
    int idx = blockIdx.x * 256 + threadIdx.x;
    int hw = h * h;
    int p = idx & (hw - 1);
    int bc = idx >> (2 * hShift);
    int oy = p >> hShift, ox = p & (h - 1);
    const float* src = x + (bc << 12) + (oy * s) * W + ox * s;
    float sum = 0.0f;
    for (int dy = 0; dy < s; ++dy)
        for (int dx = 0; dx < s; ++dx)
            sum += src[dy * W + dx];
    xs[idx] = sum * (1.0f / (s * s));
}

// GroupNorm statistics: one block per (b,g).
__global__ __launch_bounds__(256) void gn_stats_kernel(const float* __restrict__ xs,
                                                       float* __restrict__ stats,
                                                       int hw, int hwShift) {
    int bg = blockIdx.x;           // b*G + g
    int b = bg >> 3, g = bg & 7;
    int count = CPG * hw;
    const float* base = xs + ((b * C + g * CPG) << hwShift);
    float s0 = 0.0f, s1 = 0.0f, q0 = 0.0f, q1 = 0.0f;
    for (int i = threadIdx.x; i < count; i += 512) {
        float v = base[i];
        s0 += v; q0 += v * v;
        int i2 = i + 256;
        if (i2 < count) { float u = base[i2]; s1 += u; q1 += u * u; }
    }
    float s = s0 + s1, q = q0 + q1;
    __shared__ float rs[256], rs2[256];
    rs[threadIdx.x] = s; rs2[threadIdx.x] = q;
    __syncthreads();
    for (int st = 128; st > 0; st >>= 1) {
        if (threadIdx.x < st) {
            rs[threadIdx.x] += rs[threadIdx.x + st];
            rs2[threadIdx.x] += rs2[threadIdx.x + st];
        }
        __syncthreads();
    }
    if (threadIdx.x == 0) {
        float inv = 1.0f / (float)count;
        float mu = rs[0] * inv;
        float var = rs2[0] * inv - mu * mu;
        stats[bg * 2] = mu;
        stats[bg * 2 + 1] = rsqrtf(var + 1e-5f);
    }
}

// xn = (xs - mu)*rsig*gn_w[c] + gn_b[c]
__global__ __launch_bounds__(256) void xn_kernel(const float* __restrict__ xs,
                                                 const float* __restrict__ stats,
                                                 const float* __restrict__ gn_w,
                                                 const float* __restrict__ gn_b,
                                                 float* __restrict__ xn, int hwShift) {
    int idx = blockIdx.x * 256 + threadIdx.x;
    int c = (idx >> hwShift) & (C - 1);
    int b = idx >> (hwShift + 7);
    int g = c >> 4;
    float mu = stats[(b * G + g) * 2];
    float rsig = stats[(b * G + g) * 2 + 1];
    xn[idx] = (xs[idx] - mu) * rsig * gn_w[c] + gn_b[c];
}

// q,k,v projections
__global__ __launch_bounds__(256) void qkv_kernel(const float* __restrict__ xn,
                                                  const float* __restrict__ qw, const float* __restrict__ qb,
                                                  const float* __restrict__ kw, const float* __restrict__ kb,
                                                  const float* __restrict__ vw, const float* __restrict__ vb,
                                                  float* __restrict__ qkv, int N, int nShift) {
    int idx = blockIdx.x * 256 + threadIdx.x;
    int n = idx & (N - 1);
    int o = (idx >> nShift) & (INTER - 1);
    int b = (idx >> (nShift + 5)) & (B - 1);
    int proj = idx >> (nShift + 7);
    const float* wp = (proj == 0) ? qw : ((proj == 1) ? kw : vw);
    const float* bp = (proj == 0) ? qb : ((proj == 1) ? kb : vb);
    const float* xb = xn + ((b * C) << nShift);
    float a0 = 0.f, a1 = 0.f, a2 = 0.f, a3 = 0.f;
    #pragma unroll 4
    for (int c0 = 0; c0 < C; c0 += 4) {
        a0 += wp[o * C + c0]     * xb[((c0)     << nShift) + n];
        a1 += wp[o * C + c0 + 1] * xb[((c0 + 1) << nShift) + n];
        a2 += wp[o * C + c0 + 2] * xb[((c0 + 2) << nShift) + n];
        a3 += wp[o * C + c0 + 3] * xb[((c0 + 3) << nShift) + n];
    }
    qkv[idx] = (a0 + a1) + (a2 + a3) + bp[o];
}

// Split-K flash attention: each block handles 256 queries x (N/KS) keys,
// writing unnormalized partials (acc[32], m, l) per query.
template <int KS, int KSH>
__global__ __launch_bounds__(256) void attn_split_kernel(const float* __restrict__ qkv,
                                                         float* __restrict__ pacc,
                                                         float* __restrict__ pml,
                                                         int N, int nShift) {
    int ks = blockIdx.x & (KS - 1);
    int rest = blockIdx.x >> KSH;
    int nqShift = nShift - 8;                 // nq = N/256
    int qc = rest & ((1 << nqShift) - 1);
    int b = rest >> nqShift;
    int n = qc * 256 + threadIdx.x;
    int kchunk = N >> KSH;
    int kbase = ks * kchunk;

    const float* q = qkv;
    const float* k = qkv + B * INTER * N;
    const float* v = qkv + 2 * B * INTER * N;
    const float invs = 0.17677669529663687f;  // 1/sqrt(32)

    float qv[INTER], acc[INTER];
    const float* qb_ = q + (b * INTER) * N + n;
    #pragma unroll
    for (int o = 0; o < INTER; ++o) { qv[o] = qb_[o << nShift] * invs; acc[o] = 0.0f; }
    float mrun = -3.0e38f, l = 0.0f;

    __shared__ float lk[INTER * 64], lv[INTER * 64];
    const float* kb_ = k + (b * INTER) * N + kbase;
    const float* vb_ = v + (b * INTER) * N + kbase;

    for (int m0 = 0; m0 < kchunk; m0 += 64) {
        __syncthreads();
        #pragma unroll
        for (int r = 0; r < 8; ++r) {
            int e = r * 256 + threadIdx.x;     // e = o*64 + j
            int o = e >> 6, j = e & 63;
            lk[e] = kb_[(o << nShift) + m0 + j];
            lv[e] = vb_[(o << nShift) + m0 + j];
        }
        __syncthreads();
        // 8-key micro-tiles: 8 independent dots (ILP), 1 rescale per tile.
        #pragma unroll 1
        for (int j0 = 0; j0 < 64; j0 += 8) {
            float sc[8];
            #pragma unroll
            for (int jj = 0; jj < 8; ++jj) sc[jj] = 0.0f;
            #pragma unroll
            for (int o = 0; o < INTER; ++o) {
                float qo = qv[o];
                const float* lkp = lk + o * 64 + j0;
                #pragma unroll
                for (int jj = 0; jj < 8; ++jj) sc[jj] += qo * lkp[jj];
            }
            float tmax = fmaxf(fmaxf(fmaxf(sc[0], sc[1]), fmaxf(sc[2], sc[3])),
                               fmaxf(fmaxf(sc[4], sc[5]), fmaxf(sc[6], sc[7])));
            float nm = fmaxf(mrun, tmax);
            float corr = __expf(mrun - nm);
            float p[8];
            #pragma unroll
            for (int jj = 0; jj < 8; ++jj) p[jj] = __expf(sc[jj] - nm);
            float psum = ((p[0] + p[1]) + (p[2] + p[3])) + ((p[4] + p[5]) + (p[6] + p[7]));
            l = l * corr + psum;
            #pragma unroll
            for (int o = 0; o < INTER; ++o) {
                float a = acc[o] * corr;
                const float* lvp = lv + o * 64 + j0;
                #pragma unroll
                for (int jj = 0; jj < 8; ++jj) a += p[jj] * lvp[jj];
                acc[o] = a;
            }
            mrun = nm;
        }
    }
    float* pa = pacc + ((size_t)(b * KS + ks) * INTER) * N + n;
    #pragma unroll
    for (int o = 0; o < INTER; ++o) pa[o << nShift] = acc[o];
    pml[((b * KS + ks) * 2) * N + n] = mrun;
    pml[((b * KS + ks) * 2 + 1) * N + n] = l;
}

// Combine split-K partials -> att[b][o][n]
template <int KS>
__global__ __launch_bounds__(256) void combine_kernel(const float* __restrict__ pacc,
                                                      const float* __restrict__ pml,
                                                      float* __restrict__ att,
                                                      int N, int nShift) {
    int idx = blockIdx.x * 256 + threadIdx.x;
    int n = idx & (N - 1);
    int b = idx >> nShift;
    float mv[KS], lw[KS];
    float M = -3.0e38f;
    #pragma unroll
    for (int ks = 0; ks < KS; ++ks) {
        mv[ks] = pml[((b * KS + ks) * 2) * N + n];
        M = fmaxf(M, mv[ks]);
    }
    float L = 0.0f;
    #pragma unroll
    for (int ks = 0; ks < KS; ++ks) {
        float w = __expf(mv[ks] - M);
        lw[ks] = w;
        L += pml[((b * KS + ks) * 2 + 1) * N + n] * w;
    }
    float invL = 1.0f / L;
    float* ab = att + ((size_t)b * INTER) * N + n;
    #pragma unroll
    for (int o = 0; o < INTER; ++o) {
        float a = 0.0f;
        #pragma unroll
        for (int ks = 0; ks < KS; ++ks)
            a += pacc[((size_t)(b * KS + ks) * INTER + o) * N + n] * lw[ks];
        ab[o << nShift] = a * invL;
    }
}

// o = ow@att + ob; y = gamma*o + xs. If sw != null: write w0*y (s=1 -> d_out).
__global__ __launch_bounds__(256) void oy_kernel(const float* __restrict__ att,
                                                 const float* __restrict__ ow,
                                                 const float* __restrict__ ob,
                                                 const float* __restrict__ gamma,
                                                 const float* __restrict__ xs,
                                                 float* __restrict__ ydst,
                                                 const float* __restrict__ sw,
                                                 int N, int nShift) {
    int idx = blockIdx.x * 256 + threadIdx.x;
    int n = idx & (N - 1);
    int c = (idx >> nShift) & (C - 1);
    int b = idx >> (nShift + 7);
    float acc = ob[c];
    const float* ab = att + ((size_t)(b * INTER) << nShift) + n;
    #pragma unroll
    for (int i = 0; i < INTER; ++i) acc += ow[c * INTER + i] * ab[i << nShift];
    float y = gamma[0] * acc + xs[idx];
    if (sw) {
        float w0, w1, w2; scale_wts(sw, w0, w1, w2);
        ydst[idx] = w0 * y;
    } else {
        ydst[idx] = y;
    }
}

__device__ __forceinline__ float bilerp(const float* __restrict__ img, int in,
                                        int oy, int ox, float r) {
    float cy = (oy + 0.5f) * r - 0.5f;
    cy = fminf(fmaxf(cy, 0.0f), (float)(in - 1));
    float cx = (ox + 0.5f) * r - 0.5f;
    cx = fminf(fmaxf(cx, 0.0f), (float)(in - 1));
    int y0 = (int)cy; int y1i = (y0 + 1 < in) ? y0 + 1 : in - 1; float ty = cy - (float)y0;
    int x0 = (int)cx; int x1i = (x0 + 1 < in) ? x0 + 1 : in - 1; float tx = cx - (float)x0;
    float v00 = img[y0 * in + x0];
    float v01 = img[y0 * in + x1i];
    float v10 = img[y1i * in + x0];
    float v11 = img[y1i * in + x1i];
    float top = v00 * (1.0f - tx) + v01 * tx;
    float bot = v10 * (1.0f - tx) + v11 * tx;
    return top * (1.0f - ty) + bot * ty;
}

// out += w1*up(y2) + w2*up(y4)
__global__ __launch_bounds__(256) void fuse_kernel(float* __restrict__ out,
                                                   const float* __restrict__ y2,
                                                   const float* __restrict__ y4,
                                                   const float* __restrict__ sw) {
    int idx = blockIdx.x * 256 + threadIdx.x;    // B*C*4096
    int p = idx & 4095;
    int bc = idx >> 12;
    int oy = p >> 6, ox = p & 63;
    float w0, w1, w2; scale_wts(sw, w0, w1, w2);
    float v2 = bilerp(y2 + bc * 1024, 32, oy, ox, 0.5f);
    float v4 = bilerp(y4 + bc * 256, 16, oy, ox, 0.25f);
    out[idx] = out[idx] + w1 * v2 + w2 * v4;
}

extern "C" void kernel_launch(void* const* d_in, const int* in_sizes, int n_in,
                              void* d_out, int out_size, void* d_ws, size_t ws_size,
                              hipStream_t stream) {
    const float* x     = (const float*)d_in[0];
    const float* gn_w  = (const float*)d_in[1];
    const float* gn_b  = (const float*)d_in[2];
    const float* qw    = (const float*)d_in[3];
    const float* qb    = (const float*)d_in[4];
    const float* kw    = (const float*)d_in[5];
    const float* kb    = (const float*)d_in[6];
    const float* vw    = (const float*)d_in[7];
    const float* vb    = (const float*)d_in[8];
    const float* ow    = (const float*)d_in[9];
    const float* ob    = (const float*)d_in[10];
    const float* gamma = (const float*)d_in[11];
    const float* sw    = (const float*)d_in[12];
    float* out = (float*)d_out;

    float* ws    = (float*)d_ws;
    float* xs2   = ws;                                   // 524288
    float* xs4   = xs2 + B * C * 32 * 32;                // 131072
    float* xn    = xs4 + B * C * 16 * 16;                // 2097152
    float* qkvb  = xn + B * C * 64 * 64;                 // 1572864
    float* attb  = qkvb + 3 * B * INTER * 64 * 64;       // 524288
    float* y2    = attb + B * INTER * 64 * 64;           // 524288
    float* y4    = y2 + B * C * 32 * 32;                 // 131072
    float* stats = y4 + B * C * 16 * 16;                 // 64
    float* pacc  = stats + 64;                           // 4*8*32*4096 = 4194304
    float* pml   = pacc + B * 8 * INTER * 64 * 64;       // 4*8*2*4096  = 262144

    avgpool_kernel<<<B * C * 32 * 32 / 256, 256, 0, stream>>>(x, xs2, 2, 32, 5);
    avgpool_kernel<<<B * C * 16 * 16 / 256, 256, 0, stream>>>(x, xs4, 4, 16, 4);

    for (int i = 0; i < 3; ++i) {
        int hwShift = (i == 0) ? 12 : ((i == 1) ? 10 : 8);
        int hw = 1 << hwShift;
        const float* xsp = (i == 0) ? x : ((i == 1) ? xs2 : xs4);

        gn_stats_kernel<<<B * G, 256, 0, stream>>>(xsp, stats, hw, hwShift);
        xn_kernel<<<B * C * hw / 256, 256, 0, stream>>>(xsp, stats, gn_w + i * C, gn_b + i * C,
                                                        xn, hwShift);
        qkv_kernel<<<3 * B * INTER * hw / 256, 256, 0, stream>>>(
            xn, qw + i * INTER * C, qb + i * INTER,
            kw + i * INTER * C, kb + i * INTER,
            vw + i * INTER * C, vb + i * INTER, qkvb, hw, hwShift);

        int nq = hw >> 8;
        if (i < 2) {
            attn_split_kernel<8, 3><<<B * nq * 8, 256, 0, stream>>>(qkvb, pacc, pml, hw, hwShift);
            combine_kernel<8><<<B * hw / 256, 256, 0, stream>>>(pacc, pml, attb, hw, hwShift);
        } else {
            attn_split_kernel<4, 2><<<B * nq * 4, 256, 0, stream>>>(qkvb, pacc, pml, hw, hwShift);
            combine_kernel<4><<<B * hw / 256, 256, 0, stream>>>(pacc, pml, attb, hw, hwShift);
        }

        if (i == 0) {
            oy_kernel<<<B * C * hw / 256, 256, 0, stream>>>(
                attb, ow + i * C * INTER, ob + i * C, gamma + i, xsp, out, sw, hw, hwShift);
        } else {
            oy_kernel<<<B * C * hw / 256, 256, 0, stream>>>(
                attb, ow + i * C * INTER, ob + i * C, gamma + i, xsp,
                (i == 1) ? y2 : y4, nullptr, hw, hwShift);
        }
    }
    fuse_kernel<<<B * C * H * W / 256, 256, 0, stream>>>(out, y2, y4, sw);
}

// Round 3
// 234.096 us; speedup vs baseline: 9.4690x; 1.9406x over previous
//
#include <hip/hip_runtime.h>
#include <math.h>

#define B 4
#define C 128
#define H 64
#define W 64
#define G 8
#define CPG 16
#define INTER 32

typedef unsigned short ushort_t;
typedef __attribute__((ext_vector_type(8))) short short8;
typedef __attribute__((ext_vector_type(4))) short short4v;
typedef __attribute__((ext_vector_type(4))) float f32x4;

__device__ __forceinline__ ushort_t f2bf(float f) {
    union { float f; unsigned u; } x; x.f = f;
    unsigned r = x.u + 0x7fffu + ((x.u >> 16) & 1u);
    return (ushort_t)(r >> 16);
}

__device__ __forceinline__ void scale_wts(const float* __restrict__ sw,
                                          float& w0, float& w1, float& w2) {
    float a = sw[0], b = sw[1], c = sw[2];
    float m = fmaxf(a, fmaxf(b, c));
    float e0 = __expf(a - m), e1 = __expf(b - m), e2 = __expf(c - m);
    float inv = 1.0f / (e0 + e1 + e2);
    w0 = e0 * inv; w1 = e1 * inv; w2 = e2 * inv;
}

// Average-pool x (B,C,64,64) -> xs (B,C,h,h), s = 64/h.
__global__ __launch_bounds__(256) void avgpool_kernel(const float* __restrict__ x,
                                                      float* __restrict__ xs,
                                                      int s, int h, int hShift) {
    int idx = blockIdx.x * 256 + threadIdx.x;
    int hw = h * h;
    int p = idx & (hw - 1);
    int bc = idx >> (2 * hShift);
    int oy = p >> hShift, ox = p & (h - 1);
    const float* src = x + (bc << 12) + (oy * s) * W + ox * s;
    float sum = 0.0f;
    for (int dy = 0; dy < s; ++dy)
        for (int dx = 0; dx < s; ++dx)
            sum += src[dy * W + dx];
    xs[idx] = sum * (1.0f / (s * s));
}

// GroupNorm statistics: one block per (b,g).
__global__ __launch_bounds__(256) void gn_stats_kernel(const float* __restrict__ xs,
                                                       float* __restrict__ stats,
                                                       int hw, int hwShift) {
    int bg = blockIdx.x;           // b*G + g
    int b = bg >> 3, g = bg & 7;
    int count = CPG * hw;
    const float* base = xs + ((b * C + g * CPG) << hwShift);
    float s0 = 0.0f, s1 = 0.0f, q0 = 0.0f, q1 = 0.0f;
    for (int i = threadIdx.x; i < count; i += 512) {
        float v = base[i];
        s0 += v; q0 += v * v;
        int i2 = i + 256;
        if (i2 < count) { float u = base[i2]; s1 += u; q1 += u * u; }
    }
    float s = s0 + s1, q = q0 + q1;
    __shared__ float rs[256], rs2[256];
    rs[threadIdx.x] = s; rs2[threadIdx.x] = q;
    __syncthreads();
    for (int st = 128; st > 0; st >>= 1) {
        if (threadIdx.x < st) {
            rs[threadIdx.x] += rs[threadIdx.x + st];
            rs2[threadIdx.x] += rs2[threadIdx.x + st];
        }
        __syncthreads();
    }
    if (threadIdx.x == 0) {
        float inv = 1.0f / (float)count;
        float mu = rs[0] * inv;
        float var = rs2[0] * inv - mu * mu;
        stats[bg * 2] = mu;
        stats[bg * 2 + 1] = rsqrtf(var + 1e-5f);
    }
}

// xn = (xs - mu)*rsig*gn_w[c] + gn_b[c]   (fp32)
__global__ __launch_bounds__(256) void xn_kernel(const float* __restrict__ xs,
                                                 const float* __restrict__ stats,
                                                 const float* __restrict__ gn_w,
                                                 const float* __restrict__ gn_b,
                                                 float* __restrict__ xn, int hwShift) {
    int idx = blockIdx.x * 256 + threadIdx.x;
    int c = (idx >> hwShift) & (C - 1);
    int b = idx >> (hwShift + 7);
    int g = c >> 4;
    float mu = stats[(b * G + g) * 2];
    float rsig = stats[(b * G + g) * 2 + 1];
    xn[idx] = (xs[idx] - mu) * rsig * gn_w[c] + gn_b[c];
}

// q,k,v projections -> bf16. q,k in [b][n][32] layout; v in [b][32][N].
// fp32 accumulation; only the store is bf16.
__global__ __launch_bounds__(256) void qkv_bf_kernel(const float* __restrict__ xn,
    const float* __restrict__ qw, const float* __restrict__ qb,
    const float* __restrict__ kw, const float* __restrict__ kb,
    const float* __restrict__ vw, const float* __restrict__ vb,
    ushort_t* __restrict__ q_bf, ushort_t* __restrict__ k_bf, ushort_t* __restrict__ v_bf,
    int N, int nShift) {
    int nc = N >> 8;
    int bi = blockIdx.x;
    int nchunk = bi % nc; bi /= nc;
    int og = bi & 3; bi >>= 2;
    int proj = bi % 3; int b = bi / 3;
    const float* wp = (proj == 0) ? qw : ((proj == 1) ? kw : vw);
    const float* bp = (proj == 0) ? qb : ((proj == 1) ? kb : vb);
    __shared__ float wl[8 * 128];       // [c][o] layout for vector reads
    {
        int t = threadIdx.x;
        #pragma unroll
        for (int r = 0; r < 4; ++r) {
            int e = r * 256 + t;        // e = o*128 + c
            int o = e >> 7, c0 = e & 127;
            wl[c0 * 8 + o] = wp[(og * 8 + o) * C + c0];
        }
    }
    __syncthreads();
    int n = nchunk * 256 + threadIdx.x;
    const float* xb = xn + ((size_t)(b * C) << nShift) + n;
    float acc[8];
    #pragma unroll
    for (int o = 0; o < 8; ++o) acc[o] = bp[og * 8 + o];
    #pragma unroll 2
    for (int c0 = 0; c0 < C; ++c0) {
        float xv = xb[(size_t)c0 << nShift];
        const float4* wr = (const float4*)&wl[c0 * 8];
        float4 w0 = wr[0], w1 = wr[1];
        acc[0] += w0.x * xv; acc[1] += w0.y * xv; acc[2] += w0.z * xv; acc[3] += w0.w * xv;
        acc[4] += w1.x * xv; acc[5] += w1.y * xv; acc[6] += w1.z * xv; acc[7] += w1.w * xv;
    }
    if (proj < 2) {
        ushort_t tmp[8];
        #pragma unroll
        for (int o = 0; o < 8; ++o) tmp[o] = f2bf(acc[o]);
        ushort_t* dst = ((proj == 0) ? q_bf : k_bf) + ((size_t)(b * N + n)) * 32 + og * 8;
        *(uint4*)dst = *(const uint4*)tmp;
    } else {
        #pragma unroll
        for (int o = 0; o < 8; ++o)
            v_bf[((size_t)(b * 32 + og * 8 + o) << nShift) + n] = f2bf(acc[o]);
    }
}

// MFMA flash attention, split-K. Block = 4 waves; wave = 16 q-rows; 64-key tiles.
// Swapped QK^T (mfma(K,Q)) -> P rows lane-local; P via wave-private LDS; swapped PV.
template <int KS>
__global__ __launch_bounds__(256) void attn_mfma_kernel(
    const ushort_t* __restrict__ q_bf, const ushort_t* __restrict__ k_bf,
    const ushort_t* __restrict__ v_bf,
    float* __restrict__ pacc, float* __restrict__ pml, int N, int nShift) {
    __shared__ ushort_t K_lds[64 * 40];      // 64 keys x 32d, row stride 80B (pad)
    __shared__ ushort_t V_lds[32 * 72];      // 32 d x 64 keys, row stride 144B (pad)
    __shared__ ushort_t P_lds[4 * 16 * 72];  // per-wave 16 q x 64 keys, stride 144B

    int bi = blockIdx.x;
    int ks = bi % KS; bi /= KS;
    int nqc = N >> 6;
    int qc = bi % nqc; int b = bi / nqc;
    int tid = threadIdx.x;
    int l = tid & 63, w = tid >> 6, lq = l & 15, g = l >> 4;
    int q0 = qc * 64 + w * 16;
    const float invs = 0.17677669529663687f;   // 1/sqrt(32)

    short8 qf = *(const short8*)(q_bf + ((size_t)(b * N + q0 + lq)) * 32 + g * 8);
    f32x4 acco0 = {0.f, 0.f, 0.f, 0.f}, acco1 = {0.f, 0.f, 0.f, 0.f};
    float mrun = -3.0e38f, lrun = 0.0f;

    int kchunk = N / KS;
    int kbase = ks * kchunk;
    int ntiles = kchunk >> 6;
    ushort_t* Pw = P_lds + w * 16 * 72;

    for (int t = 0; t < ntiles; ++t) {
        int kt0 = kbase + t * 64;
        __syncthreads();
        {
            const uint4* ksrc = (const uint4*)(k_bf + ((size_t)(b * N + kt0 + (tid >> 2))) * 32 + (tid & 3) * 8);
            *(uint4*)&K_lds[(tid >> 2) * 40 + (tid & 3) * 8] = *ksrc;
            const uint4* vsrc = (const uint4*)(v_bf + (((size_t)(b * 32 + (tid >> 3))) << nShift) + kt0 + (tid & 7) * 8);
            *(uint4*)&V_lds[(tid >> 3) * 72 + (tid & 7) * 8] = *vsrc;
        }
        __syncthreads();

        // S^T = K · Q^T : lane holds S[q=lq][key = kt*16 + g*4 + r]
        f32x4 sa[4];
        #pragma unroll
        for (int kt = 0; kt < 4; ++kt) {
            short8 kf = *(const short8*)&K_lds[(kt * 16 + lq) * 40 + g * 8];
            f32x4 z = {0.f, 0.f, 0.f, 0.f};
            sa[kt] = __builtin_amdgcn_mfma_f32_16x16x32_bf16(kf, qf, z, 0, 0, 0);
        }
        // online softmax over this 64-key tile
        float sc[16];
        #pragma unroll
        for (int kt = 0; kt < 4; ++kt) {
            sc[kt * 4 + 0] = sa[kt][0] * invs;
            sc[kt * 4 + 1] = sa[kt][1] * invs;
            sc[kt * 4 + 2] = sa[kt][2] * invs;
            sc[kt * 4 + 3] = sa[kt][3] * invs;
        }
        float tmax = sc[0];
        #pragma unroll
        for (int j = 1; j < 16; ++j) tmax = fmaxf(tmax, sc[j]);
        tmax = fmaxf(tmax, __shfl_xor(tmax, 16, 64));
        tmax = fmaxf(tmax, __shfl_xor(tmax, 32, 64));
        float nm = fmaxf(mrun, tmax);
        float corr = __expf(mrun - nm);
        float psum = 0.0f;
        ushort_t pb[16];
        #pragma unroll
        for (int j = 0; j < 16; ++j) {
            float p = __expf(sc[j] - nm);
            psum += p;
            pb[j] = f2bf(p);
        }
        psum += __shfl_xor(psum, 16, 64);
        psum += __shfl_xor(psum, 32, 64);
        lrun = lrun * corr + psum;
        mrun = nm;
        #pragma unroll
        for (int e = 0; e < 4; ++e) { acco0[e] *= corr; acco1[e] *= corr; }
        // write P (bf16) to wave-private LDS: row q=lq, col key
        #pragma unroll
        for (int kt = 0; kt < 4; ++kt) {
            short4v pv4;
            pv4[0] = (short)pb[kt * 4 + 0];
            pv4[1] = (short)pb[kt * 4 + 1];
            pv4[2] = (short)pb[kt * 4 + 2];
            pv4[3] = (short)pb[kt * 4 + 3];
            *(short4v*)&Pw[lq * 72 + kt * 16 + g * 4] = pv4;
        }
        // O^T += V^T · P^T  (2 chunks of 32 keys x 2 d-tiles)
        #pragma unroll
        for (int c = 0; c < 2; ++c) {
            short8 pf  = *(const short8*)&Pw[lq * 72 + c * 32 + g * 8];
            short8 vf0 = *(const short8*)&V_lds[(lq) * 72 + c * 32 + g * 8];
            short8 vf1 = *(const short8*)&V_lds[(16 + lq) * 72 + c * 32 + g * 8];
            acco0 = __builtin_amdgcn_mfma_f32_16x16x32_bf16(vf0, pf, acco0, 0, 0, 0);
            acco1 = __builtin_amdgcn_mfma_f32_16x16x32_bf16(vf1, pf, acco1, 0, 0, 0);
        }
    }
    // epilogue: unnormalized partials + (m,l)
    int n = q0 + lq;
    size_t pb_ = ((size_t)(b * KS + ks)) * 32;
    #pragma unroll
    for (int r = 0; r < 4; ++r) {
        pacc[(pb_ + (g * 4 + r)) * N + n]      = acco0[r];
        pacc[(pb_ + 16 + (g * 4 + r)) * N + n] = acco1[r];
    }
    if (g == 0) {
        pml[((size_t)(b * KS + ks) * 2) * N + n]     = mrun;
        pml[((size_t)(b * KS + ks) * 2 + 1) * N + n] = lrun;
    }
}

// Combine split-K partials -> att[b][o][n] (fp32)
template <int KS>
__global__ __launch_bounds__(256) void combine_kernel(const float* __restrict__ pacc,
                                                      const float* __restrict__ pml,
                                                      float* __restrict__ att,
                                                      int N, int nShift) {
    int idx = blockIdx.x * 256 + threadIdx.x;
    int n = idx & (N - 1);
    int b = idx >> nShift;
    float mv[KS], lw[KS];
    float M = -3.0e38f;
    #pragma unroll
    for (int ks = 0; ks < KS; ++ks) {
        mv[ks] = pml[((size_t)(b * KS + ks) * 2) * N + n];
        M = fmaxf(M, mv[ks]);
    }
    float L = 0.0f;
    #pragma unroll
    for (int ks = 0; ks < KS; ++ks) {
        float wgt = __expf(mv[ks] - M);
        lw[ks] = wgt;
        L += pml[((size_t)(b * KS + ks) * 2 + 1) * N + n] * wgt;
    }
    float invL = 1.0f / L;
    float* ab = att + ((size_t)b * INTER) * N + n;
    #pragma unroll
    for (int o = 0; o < INTER; ++o) {
        float a = 0.0f;
        #pragma unroll
        for (int ks = 0; ks < KS; ++ks)
            a += pacc[((size_t)(b * KS + ks) * INTER + o) * N + n] * lw[ks];
        ab[o << nShift] = a * invL;
    }
}

// o = ow@att + ob; y = gamma*o + xs. If sw != null: write w0*y (s=1 -> d_out).
__global__ __launch_bounds__(256) void oy_kernel(const float* __restrict__ att,
                                                 const float* __restrict__ ow,
                                                 const float* __restrict__ ob,
                                                 const float* __restrict__ gamma,
                                                 const float* __restrict__ xs,
                                                 float* __restrict__ ydst,
                                                 const float* __restrict__ sw,
                                                 int N, int nShift) {
    int idx = blockIdx.x * 256 + threadIdx.x;
    int n = idx & (N - 1);
    int c = (idx >> nShift) & (C - 1);
    int b = idx >> (nShift + 7);
    float acc = ob[c];
    const float* ab = att + ((size_t)(b * INTER) << nShift) + n;
    #pragma unroll
    for (int i = 0; i < INTER; ++i) acc += ow[c * INTER + i] * ab[i << nShift];
    float y = gamma[0] * acc + xs[idx];
    if (sw) {
        float w0, w1, w2; scale_wts(sw, w0, w1, w2);
        ydst[idx] = w0 * y;
    } else {
        ydst[idx] = y;
    }
}

__device__ __forceinline__ float bilerp(const float* __restrict__ img, int in,
                                        int oy, int ox, float r) {
    float cy = (oy + 0.5f) * r - 0.5f;
    cy = fminf(fmaxf(cy, 0.0f), (float)(in - 1));
    float cx = (ox + 0.5f) * r - 0.5f;
    cx = fminf(fmaxf(cx, 0.0f), (float)(in - 1));
    int y0 = (int)cy; int y1i = (y0 + 1 < in) ? y0 + 1 : in - 1; float ty = cy - (float)y0;
    int x0 = (int)cx; int x1i = (x0 + 1 < in) ? x0 + 1 : in - 1; float tx = cx - (float)x0;
    float v00 = img[y0 * in + x0];
    float v01 = img[y0 * in + x1i];
    float v10 = img[y1i * in + x0];
    float v11 = img[y1i * in + x1i];
    float top = v00 * (1.0f - tx) + v01 * tx;
    float bot = v10 * (1.0f - tx) + v11 * tx;
    return top * (1.0f - ty) + bot * ty;
}

// out += w1*up(y2) + w2*up(y4)
__global__ __launch_bounds__(256) void fuse_kernel(float* __restrict__ out,
                                                   const float* __restrict__ y2,
                                                   const float* __restrict__ y4,
                                                   const float* __restrict__ sw) {
    int idx = blockIdx.x * 256 + threadIdx.x;    // B*C*4096
    int p = idx & 4095;
    int bc = idx >> 12;
    int oy = p >> 6, ox = p & 63;
    float w0, w1, w2; scale_wts(sw, w0, w1, w2);
    float v2 = bilerp(y2 + bc * 1024, 32, oy, ox, 0.5f);
    float v4 = bilerp(y4 + bc * 256, 16, oy, ox, 0.25f);
    out[idx] = out[idx] + w1 * v2 + w2 * v4;
}

extern "C" void kernel_launch(void* const* d_in, const int* in_sizes, int n_in,
                              void* d_out, int out_size, void* d_ws, size_t ws_size,
                              hipStream_t stream) {
    const float* x     = (const float*)d_in[0];
    const float* gn_w  = (const float*)d_in[1];
    const float* gn_b  = (const float*)d_in[2];
    const float* qw    = (const float*)d_in[3];
    const float* qb    = (const float*)d_in[4];
    const float* kw    = (const float*)d_in[5];
    const float* kb    = (const float*)d_in[6];
    const float* vw    = (const float*)d_in[7];
    const float* vb    = (const float*)d_in[8];
    const float* ow    = (const float*)d_in[9];
    const float* ob    = (const float*)d_in[10];
    const float* gamma = (const float*)d_in[11];
    const float* sw    = (const float*)d_in[12];
    float* out = (float*)d_out;

    float* ws    = (float*)d_ws;
    float* xs2   = ws;                                   // 524288
    float* xs4   = xs2 + B * C * 32 * 32;                // 131072
    float* xn    = xs4 + B * C * 16 * 16;                // 2097152
    float* attb  = xn + B * C * 64 * 64;                 // 524288
    float* y2    = attb + B * INTER * 64 * 64;           // 524288
    float* y4    = y2 + B * C * 32 * 32;                 // 131072
    float* stats = y4 + B * C * 16 * 16;                 // 64
    float* pacc  = stats + 64;                           // 4*4*32*4096 = 2097152
    float* pml   = pacc + B * 4 * INTER * 64 * 64;       // 4*4*2*4096  = 131072
    ushort_t* qbf = (ushort_t*)(pml + B * 4 * 2 * 64 * 64);
    ushort_t* kbf = qbf + B * INTER * 64 * 64;           // 524288 ushorts each
    ushort_t* vbf = kbf + B * INTER * 64 * 64;

    avgpool_kernel<<<B * C * 32 * 32 / 256, 256, 0, stream>>>(x, xs2, 2, 32, 5);
    avgpool_kernel<<<B * C * 16 * 16 / 256, 256, 0, stream>>>(x, xs4, 4, 16, 4);

    for (int i = 0; i < 3; ++i) {
        int hwShift = (i == 0) ? 12 : ((i == 1) ? 10 : 8);
        int hw = 1 << hwShift;
        const float* xsp = (i == 0) ? x : ((i == 1) ? xs2 : xs4);

        gn_stats_kernel<<<B * G, 256, 0, stream>>>(xsp, stats, hw, hwShift);
        xn_kernel<<<B * C * hw / 256, 256, 0, stream>>>(xsp, stats, gn_w + i * C, gn_b + i * C,
                                                        xn, hwShift);
        qkv_bf_kernel<<<B * 12 * (hw >> 8), 256, 0, stream>>>(
            xn, qw + i * INTER * C, qb + i * INTER,
            kw + i * INTER * C, kb + i * INTER,
            vw + i * INTER * C, vb + i * INTER,
            qbf, kbf, vbf, hw, hwShift);

        attn_mfma_kernel<4><<<B * (hw >> 6) * 4, 256, 0, stream>>>(
            qbf, kbf, vbf, pacc, pml, hw, hwShift);
        combine_kernel<4><<<B * hw / 256, 256, 0, stream>>>(pacc, pml, attb, hw, hwShift);

        if (i == 0) {
            oy_kernel<<<B * C * hw / 256, 256, 0, stream>>>(
                attb, ow + i * C * INTER, ob + i * C, gamma + i, xsp, out, sw, hw, hwShift);
        } else {
            oy_kernel<<<B * C * hw / 256, 256, 0, stream>>>(
                attb, ow + i * C * INTER, ob + i * C, gamma + i, xsp,
                (i == 1) ? y2 : y4, nullptr, hw, hwShift);
        }
    }
    fuse_kernel<<<B * C * H * W / 256, 256, 0, stream>>>(out, y2, y4, sw);
}

// Round 4
// 176.703 us; speedup vs baseline: 12.5445x; 1.3248x over previous
//
#include <hip/hip_runtime.h>
#include <math.h>

#define B 4
#define C 128
#define H 64
#define W 64
#define G 8
#define CPG 16
#define INTER 32
#define SPLIT 16

typedef unsigned short ushort_t;
typedef __attribute__((ext_vector_type(8))) short short8;
typedef __attribute__((ext_vector_type(4))) short short4v;
typedef __attribute__((ext_vector_type(4))) float f32x4;

__device__ __forceinline__ ushort_t f2bf(float f) {
    union { float f; unsigned u; } x; x.f = f;
    unsigned r = x.u + 0x7fffu + ((x.u >> 16) & 1u);
    return (ushort_t)(r >> 16);
}

__device__ __forceinline__ void scale_wts(const float* __restrict__ sw,
                                          float& w0, float& w1, float& w2) {
    float a = sw[0], b = sw[1], c = sw[2];
    float m = fmaxf(a, fmaxf(b, c));
    float e0 = __expf(a - m), e1 = __expf(b - m), e2 = __expf(c - m);
    float inv = 1.0f / (e0 + e1 + e2);
    w0 = e0 * inv; w1 = e1 * inv; w2 = e2 * inv;
}

// Average-pool x (B,C,64,64) -> xs (B,C,h,h), s = 64/h.
__global__ __launch_bounds__(256) void avgpool_kernel(const float* __restrict__ x,
                                                      float* __restrict__ xs,
                                                      int s, int h, int hShift) {
    int idx = blockIdx.x * 256 + threadIdx.x;
    int hw = h * h;
    int p = idx & (hw - 1);
    int bc = idx >> (2 * hShift);
    int oy = p >> hShift, ox = p & (h - 1);
    const float* src = x + (bc << 12) + (oy * s) * W + ox * s;
    float sum = 0.0f;
    for (int dy = 0; dy < s; ++dy)
        for (int dx = 0; dx < s; ++dx)
            sum += src[dy * W + dx];
    xs[idx] = sum * (1.0f / (s * s));
}

// GN stage 1: partial sums. Grid = B*G*SPLIT blocks.
__global__ __launch_bounds__(256) void gn_part_kernel(const float* __restrict__ xs,
                                                      float* __restrict__ part,
                                                      int hwShift) {
    int blk = blockIdx.x;
    int sp = blk & (SPLIT - 1);
    int bg = blk >> 4;
    int b = bg >> 3, g = bg & 7;
    int count = CPG << hwShift;
    int chunk = count >> 4;
    const float* base = xs + ((b * C + g * CPG) << hwShift) + sp * chunk;
    float s = 0.0f, q = 0.0f;
    for (int i = threadIdx.x; i < chunk; i += 256) {
        float v = base[i];
        s += v; q += v * v;
    }
    __shared__ float rs[256], rq[256];
    rs[threadIdx.x] = s; rq[threadIdx.x] = q;
    __syncthreads();
    for (int st = 128; st > 0; st >>= 1) {
        if (threadIdx.x < st) {
            rs[threadIdx.x] += rs[threadIdx.x + st];
            rq[threadIdx.x] += rq[threadIdx.x + st];
        }
        __syncthreads();
    }
    if (threadIdx.x == 0) {
        part[blk * 2]     = rs[0];
        part[blk * 2 + 1] = rq[0];
    }
}

// GN stage 2: fold partials -> per-(b,c) affine (a, b2): xn = a*xs + b2.
__global__ __launch_bounds__(256) void gn_final_kernel(const float* __restrict__ part,
                                                       const float* __restrict__ gn_w,
                                                       const float* __restrict__ gn_b,
                                                       float2* __restrict__ scsh,
                                                       int hwShift) {
    int idx = blockIdx.x * 256 + threadIdx.x;    // B*C = 512
    int c = idx & 127, b = idx >> 7;
    int bg = b * 8 + (c >> 4);
    float s = 0.0f, q = 0.0f;
    #pragma unroll
    for (int sp = 0; sp < SPLIT; ++sp) {
        s += part[(bg * SPLIT + sp) * 2];
        q += part[(bg * SPLIT + sp) * 2 + 1];
    }
    float inv = 1.0f / (float)(CPG << hwShift);
    float mu = s * inv;
    float var = q * inv - mu * mu;
    float rsig = rsqrtf(var + 1e-5f);
    float a = rsig * gn_w[c];
    float2 r; r.x = a; r.y = gn_b[c] - mu * a;
    scsh[idx] = r;
}

// q,k,v projections with fused GroupNorm -> bf16.
// q,k in [b][n][32]; v in [b][32][N]. fp32 accumulation.
__global__ __launch_bounds__(256) void qkv_bf_kernel(const float* __restrict__ xs,
    const float2* __restrict__ scsh,
    const float* __restrict__ qw, const float* __restrict__ qb,
    const float* __restrict__ kw, const float* __restrict__ kb,
    const float* __restrict__ vw, const float* __restrict__ vb,
    ushort_t* __restrict__ q_bf, ushort_t* __restrict__ k_bf, ushort_t* __restrict__ v_bf,
    int N, int nShift) {
    int nc = N >> 8;
    int bi = blockIdx.x;
    int nchunk = bi % nc; bi /= nc;
    int og = bi & 3; bi >>= 2;
    int proj = bi % 3; int b = bi / 3;
    const float* wp = (proj == 0) ? qw : ((proj == 1) ? kw : vw);
    const float* bp = (proj == 0) ? qb : ((proj == 1) ? kb : vb);
    __shared__ float wl[8 * 128];       // [c][o]
    __shared__ float2 ss[128];
    {
        int t = threadIdx.x;
        #pragma unroll
        for (int r = 0; r < 4; ++r) {
            int e = r * 256 + t;        // e = o*128 + c
            int o = e >> 7, c0 = e & 127;
            wl[c0 * 8 + o] = wp[(og * 8 + o) * C + c0];
        }
        if (t < 128) ss[t] = scsh[b * 128 + t];
    }
    __syncthreads();
    int n = nchunk * 256 + threadIdx.x;
    const float* xb = xs + ((size_t)(b * C) << nShift) + n;
    float acc[8];
    #pragma unroll
    for (int o = 0; o < 8; ++o) acc[o] = bp[og * 8 + o];
    #pragma unroll 2
    for (int c0 = 0; c0 < C; ++c0) {
        float raw = xb[(size_t)c0 << nShift];
        float2 s2 = ss[c0];
        float xv = fmaf(s2.x, raw, s2.y);
        const float4* wr = (const float4*)&wl[c0 * 8];
        float4 w0 = wr[0], w1 = wr[1];
        acc[0] += w0.x * xv; acc[1] += w0.y * xv; acc[2] += w0.z * xv; acc[3] += w0.w * xv;
        acc[4] += w1.x * xv; acc[5] += w1.y * xv; acc[6] += w1.z * xv; acc[7] += w1.w * xv;
    }
    if (proj < 2) {
        ushort_t tmp[8];
        #pragma unroll
        for (int o = 0; o < 8; ++o) tmp[o] = f2bf(acc[o]);
        ushort_t* dst = ((proj == 0) ? q_bf : k_bf) + ((size_t)(b * N + n)) * 32 + og * 8;
        *(uint4*)dst = *(const uint4*)tmp;
    } else {
        #pragma unroll
        for (int o = 0; o < 8; ++o)
            v_bf[((size_t)(b * 32 + og * 8 + o) << nShift) + n] = f2bf(acc[o]);
    }
}

// MFMA flash attention, split-K. Block = 4 waves; wave = 16 q-rows; 64-key tiles.
template <int KS>
__global__ __launch_bounds__(256) void attn_mfma_kernel(
    const ushort_t* __restrict__ q_bf, const ushort_t* __restrict__ k_bf,
    const ushort_t* __restrict__ v_bf,
    float* __restrict__ pacc, float* __restrict__ pml, int N, int nShift) {
    __shared__ ushort_t K_lds[64 * 40];      // 64 keys x 32d, row stride 80B
    __shared__ ushort_t V_lds[32 * 72];      // 32 d x 64 keys, row stride 144B
    __shared__ ushort_t P_lds[4 * 16 * 72];  // per-wave 16 q x 64 keys

    int bi = blockIdx.x;
    int ks = bi % KS; bi /= KS;
    int nqc = N >> 6;
    int qc = bi % nqc; int b = bi / nqc;
    int tid = threadIdx.x;
    int l = tid & 63, w = tid >> 6, lq = l & 15, g = l >> 4;
    int q0 = qc * 64 + w * 16;
    const float invs = 0.17677669529663687f;   // 1/sqrt(32)

    short8 qf = *(const short8*)(q_bf + ((size_t)(b * N + q0 + lq)) * 32 + g * 8);
    f32x4 acco0 = {0.f, 0.f, 0.f, 0.f}, acco1 = {0.f, 0.f, 0.f, 0.f};
    float mrun = -3.0e38f, lrun = 0.0f;

    int kchunk = N / KS;
    int kbase = ks * kchunk;
    int ntiles = kchunk >> 6;
    ushort_t* Pw = P_lds + w * 16 * 72;

    for (int t = 0; t < ntiles; ++t) {
        int kt0 = kbase + t * 64;
        __syncthreads();
        {
            const uint4* ksrc = (const uint4*)(k_bf + ((size_t)(b * N + kt0 + (tid >> 2))) * 32 + (tid & 3) * 8);
            *(uint4*)&K_lds[(tid >> 2) * 40 + (tid & 3) * 8] = *ksrc;
            const uint4* vsrc = (const uint4*)(v_bf + (((size_t)(b * 32 + (tid >> 3))) << nShift) + kt0 + (tid & 7) * 8);
            *(uint4*)&V_lds[(tid >> 3) * 72 + (tid & 7) * 8] = *vsrc;
        }
        __syncthreads();

        // S^T = K · Q^T : lane holds S[q=lq][key = kt*16 + g*4 + r]
        f32x4 sa[4];
        #pragma unroll
        for (int kt = 0; kt < 4; ++kt) {
            short8 kf = *(const short8*)&K_lds[(kt * 16 + lq) * 40 + g * 8];
            f32x4 z = {0.f, 0.f, 0.f, 0.f};
            sa[kt] = __builtin_amdgcn_mfma_f32_16x16x32_bf16(kf, qf, z, 0, 0, 0);
        }
        float sc[16];
        #pragma unroll
        for (int kt = 0; kt < 4; ++kt) {
            sc[kt * 4 + 0] = sa[kt][0] * invs;
            sc[kt * 4 + 1] = sa[kt][1] * invs;
            sc[kt * 4 + 2] = sa[kt][2] * invs;
            sc[kt * 4 + 3] = sa[kt][3] * invs;
        }
        float tmax = sc[0];
        #pragma unroll
        for (int j = 1; j < 16; ++j) tmax = fmaxf(tmax, sc[j]);
        tmax = fmaxf(tmax, __shfl_xor(tmax, 16, 64));
        tmax = fmaxf(tmax, __shfl_xor(tmax, 32, 64));
        float nm = fmaxf(mrun, tmax);
        float corr = __expf(mrun - nm);
        float psum = 0.0f;
        ushort_t pb[16];
        #pragma unroll
        for (int j = 0; j < 16; ++j) {
            float p = __expf(sc[j] - nm);
            psum += p;
            pb[j] = f2bf(p);
        }
        psum += __shfl_xor(psum, 16, 64);
        psum += __shfl_xor(psum, 32, 64);
        lrun = lrun * corr + psum;
        mrun = nm;
        #pragma unroll
        for (int e = 0; e < 4; ++e) { acco0[e] *= corr; acco1[e] *= corr; }
        #pragma unroll
        for (int kt = 0; kt < 4; ++kt) {
            short4v pv4;
            pv4[0] = (short)pb[kt * 4 + 0];
            pv4[1] = (short)pb[kt * 4 + 1];
            pv4[2] = (short)pb[kt * 4 + 2];
            pv4[3] = (short)pb[kt * 4 + 3];
            *(short4v*)&Pw[lq * 72 + kt * 16 + g * 4] = pv4;
        }
        #pragma unroll
        for (int c = 0; c < 2; ++c) {
            short8 pf  = *(const short8*)&Pw[lq * 72 + c * 32 + g * 8];
            short8 vf0 = *(const short8*)&V_lds[(lq) * 72 + c * 32 + g * 8];
            short8 vf1 = *(const short8*)&V_lds[(16 + lq) * 72 + c * 32 + g * 8];
            acco0 = __builtin_amdgcn_mfma_f32_16x16x32_bf16(vf0, pf, acco0, 0, 0, 0);
            acco1 = __builtin_amdgcn_mfma_f32_16x16x32_bf16(vf1, pf, acco1, 0, 0, 0);
        }
    }
    int n = q0 + lq;
    size_t pb_ = ((size_t)(b * KS + ks)) * 32;
    #pragma unroll
    for (int r = 0; r < 4; ++r) {
        pacc[(pb_ + (g * 4 + r)) * N + n]      = acco0[r];
        pacc[(pb_ + 16 + (g * 4 + r)) * N + n] = acco1[r];
    }
    if (g == 0) {
        pml[((size_t)(b * KS + ks) * 2) * N + n]     = mrun;
        pml[((size_t)(b * KS + ks) * 2 + 1) * N + n] = lrun;
    }
}

// Combine split-K partials -> att[b][o][n]. One thread per (b,o,n).
template <int KS>
__global__ __launch_bounds__(256) void combine_kernel(const float* __restrict__ pacc,
                                                      const float* __restrict__ pml,
                                                      float* __restrict__ att,
                                                      int N, int nShift) {
    int idx = blockIdx.x * 256 + threadIdx.x;    // B*32*N total
    int n = idx & (N - 1);
    int o = (idx >> nShift) & 31;
    int b = idx >> (nShift + 5);
    float mv[KS];
    float M = -3.0e38f;
    #pragma unroll
    for (int ks = 0; ks < KS; ++ks) {
        mv[ks] = pml[((size_t)(b * KS + ks) * 2) * N + n];
        M = fmaxf(M, mv[ks]);
    }
    float L = 0.0f, a = 0.0f;
    #pragma unroll
    for (int ks = 0; ks < KS; ++ks) {
        float wgt = __expf(mv[ks] - M);
        L += pml[((size_t)(b * KS + ks) * 2 + 1) * N + n] * wgt;
        a += pacc[((size_t)(b * KS + ks) * INTER + o) * N + n] * wgt;
    }
    att[((size_t)(b * INTER + o) << nShift) + n] = a / L;
}

// o = ow@att + ob; y = gamma*o + xs. If sw != null: write w0*y (s=1 -> d_out).
__global__ __launch_bounds__(256) void oy_kernel(const float* __restrict__ att,
                                                 const float* __restrict__ ow,
                                                 const float* __restrict__ ob,
                                                 const float* __restrict__ gamma,
                                                 const float* __restrict__ xs,
                                                 float* __restrict__ ydst,
                                                 const float* __restrict__ sw,
                                                 int N, int nShift) {
    int idx = blockIdx.x * 256 + threadIdx.x;
    int n = idx & (N - 1);
    int c = (idx >> nShift) & (C - 1);
    int b = idx >> (nShift + 7);
    float acc = ob[c];
    const float* ab = att + ((size_t)(b * INTER) << nShift) + n;
    #pragma unroll
    for (int i = 0; i < INTER; ++i) acc += ow[c * INTER + i] * ab[i << nShift];
    float y = gamma[0] * acc + xs[idx];
    if (sw) {
        float w0, w1, w2; scale_wts(sw, w0, w1, w2);
        ydst[idx] = w0 * y;
    } else {
        ydst[idx] = y;
    }
}

__device__ __forceinline__ float bilerp(const float* __restrict__ img, int in,
                                        int oy, int ox, float r) {
    float cy = (oy + 0.5f) * r - 0.5f;
    cy = fminf(fmaxf(cy, 0.0f), (float)(in - 1));
    float cx = (ox + 0.5f) * r - 0.5f;
    cx = fminf(fmaxf(cx, 0.0f), (float)(in - 1));
    int y0 = (int)cy; int y1i = (y0 + 1 < in) ? y0 + 1 : in - 1; float ty = cy - (float)y0;
    int x0 = (int)cx; int x1i = (x0 + 1 < in) ? x0 + 1 : in - 1; float tx = cx - (float)x0;
    float v00 = img[y0 * in + x0];
    float v01 = img[y0 * in + x1i];
    float v10 = img[y1i * in + x0];
    float v11 = img[y1i * in + x1i];
    float top = v00 * (1.0f - tx) + v01 * tx;
    float bot = v10 * (1.0f - tx) + v11 * tx;
    return top * (1.0f - ty) + bot * ty;
}

// out += w1*up(y2) + w2*up(y4)
__global__ __launch_bounds__(256) void fuse_kernel(float* __restrict__ out,
                                                   const float* __restrict__ y2,
                                                   const float* __restrict__ y4,
                                                   const float* __restrict__ sw) {
    int idx = blockIdx.x * 256 + threadIdx.x;    // B*C*4096
    int p = idx & 4095;
    int bc = idx >> 12;
    int oy = p >> 6, ox = p & 63;
    float w0, w1, w2; scale_wts(sw, w0, w1, w2);
    float v2 = bilerp(y2 + bc * 1024, 32, oy, ox, 0.5f);
    float v4 = bilerp(y4 + bc * 256, 16, oy, ox, 0.25f);
    out[idx] = out[idx] + w1 * v2 + w2 * v4;
}

extern "C" void kernel_launch(void* const* d_in, const int* in_sizes, int n_in,
                              void* d_out, int out_size, void* d_ws, size_t ws_size,
                              hipStream_t stream) {
    const float* x     = (const float*)d_in[0];
    const float* gn_w  = (const float*)d_in[1];
    const float* gn_b  = (const float*)d_in[2];
    const float* qw    = (const float*)d_in[3];
    const float* qb    = (const float*)d_in[4];
    const float* kw    = (const float*)d_in[5];
    const float* kb    = (const float*)d_in[6];
    const float* vw    = (const float*)d_in[7];
    const float* vb    = (const float*)d_in[8];
    const float* ow    = (const float*)d_in[9];
    const float* ob    = (const float*)d_in[10];
    const float* gamma = (const float*)d_in[11];
    const float* sw    = (const float*)d_in[12];
    float* out = (float*)d_out;

    float* ws    = (float*)d_ws;
    float* xs2   = ws;                                   // 524288
    float* xs4   = xs2 + B * C * 32 * 32;                // 131072
    float* attb  = xs4 + B * C * 16 * 16;                // 524288
    float* y2    = attb + B * INTER * 64 * 64;           // 524288
    float* y4    = y2 + B * C * 32 * 32;                 // 131072
    float* part  = y4 + B * C * 16 * 16;                 // 1024
    float* scshf = part + 1024;                          // 1024 (float2[512])
    float* pacc  = scshf + 1024;                         // 4*4*32*4096 = 2097152
    float* pml   = pacc + B * 4 * INTER * 64 * 64;       // 4*4*2*4096  = 131072
    ushort_t* qbf = (ushort_t*)(pml + B * 4 * 2 * 64 * 64);
    ushort_t* kbf = qbf + B * INTER * 64 * 64;           // 524288 ushorts each
    ushort_t* vbf = kbf + B * INTER * 64 * 64;
    float2* scsh = (float2*)scshf;

    avgpool_kernel<<<B * C * 32 * 32 / 256, 256, 0, stream>>>(x, xs2, 2, 32, 5);
    avgpool_kernel<<<B * C * 16 * 16 / 256, 256, 0, stream>>>(x, xs4, 4, 16, 4);

    for (int i = 0; i < 3; ++i) {
        int hwShift = (i == 0) ? 12 : ((i == 1) ? 10 : 8);
        int hw = 1 << hwShift;
        const float* xsp = (i == 0) ? x : ((i == 1) ? xs2 : xs4);

        gn_part_kernel<<<B * G * SPLIT, 256, 0, stream>>>(xsp, part, hwShift);
        gn_final_kernel<<<2, 256, 0, stream>>>(part, gn_w + i * C, gn_b + i * C, scsh, hwShift);

        qkv_bf_kernel<<<B * 12 * (hw >> 8), 256, 0, stream>>>(
            xsp, scsh, qw + i * INTER * C, qb + i * INTER,
            kw + i * INTER * C, kb + i * INTER,
            vw + i * INTER * C, vb + i * INTER,
            qbf, kbf, vbf, hw, hwShift);

        attn_mfma_kernel<4><<<B * (hw >> 6) * 4, 256, 0, stream>>>(
            qbf, kbf, vbf, pacc, pml, hw, hwShift);
        combine_kernel<4><<<B * INTER * hw / 256, 256, 0, stream>>>(pacc, pml, attb, hw, hwShift);

        if (i == 0) {
            oy_kernel<<<B * C * hw / 256, 256, 0, stream>>>(
                attb, ow + i * C * INTER, ob + i * C, gamma + i, xsp, out, sw, hw, hwShift);
        } else {
            oy_kernel<<<B * C * hw / 256, 256, 0, stream>>>(
                attb, ow + i * C * INTER, ob + i * C, gamma + i, xsp,
                (i == 1) ? y2 : y4, nullptr, hw, hwShift);
        }
    }
    fuse_kernel<<<B * C * H * W / 256, 256, 0, stream>>>(out, y2, y4, sw);
}

// Round 5
// 105.086 us; speedup vs baseline: 21.0939x; 1.6815x over previous
//
#include <hip/hip_runtime.h>
#include <math.h>

#define B 4
#define C 128
#define G 8
#define CPG 16
#define INTER 32
#define SPLIT 16
#define KS 4

#define N1 4096
#define N2 1024
#define N4 256

// element offsets (compile-time)
#define QOFF2 (B * N1 * 32)                  // 524288
#define QOFF4 (QOFF2 + B * N2 * 32)          // 655360
#define QTOT  (QOFF4 + B * N4 * 32)          // 688128
#define PAOFF2 (B * KS * 32 * N1)            // 2097152
#define PAOFF4 (PAOFF2 + B * KS * 32 * N2)   // 2621440
#define PATOT  (PAOFF4 + B * KS * 32 * N4)   // 2752512
#define PMOFF2 (B * KS * 2 * N1)             // 131072
#define PMOFF4 (PMOFF2 + B * KS * 2 * N2)    // 163840
#define PMTOT  (PMOFF4 + B * KS * 2 * N4)    // 172032

typedef unsigned short ushort_t;
typedef __attribute__((ext_vector_type(8))) short short8;
typedef __attribute__((ext_vector_type(4))) short short4v;
typedef __attribute__((ext_vector_type(4))) float f32x4;

__device__ __forceinline__ ushort_t f2bf(float f) {
    union { float f; unsigned u; } x; x.f = f;
    unsigned r = x.u + 0x7fffu + ((x.u >> 16) & 1u);
    return (ushort_t)(r >> 16);
}

__device__ __forceinline__ void scale_wts(const float* __restrict__ sw,
                                          float& w0, float& w1, float& w2) {
    float a = sw[0], b = sw[1], c = sw[2];
    float m = fmaxf(a, fmaxf(b, c));
    float e0 = __expf(a - m), e1 = __expf(b - m), e2 = __expf(c - m);
    float inv = 1.0f / (e0 + e1 + e2);
    w0 = e0 * inv; w1 = e1 * inv; w2 = e2 * inv;
}

// ---------- avgpool: both scales in one launch ----------
__global__ __launch_bounds__(256) void avgpool_all_kernel(const float* __restrict__ x,
                                                          float* __restrict__ xs2,
                                                          float* __restrict__ xs4) {
    int bid = blockIdx.x;
    if (bid < 2048) {                // s=2, h=32
        int idx = bid * 256 + threadIdx.x;
        int p = idx & 1023;
        int bc = idx >> 10;
        int oy = p >> 5, ox = p & 31;
        const float* src = x + (bc << 12) + (oy * 2) * 64 + ox * 2;
        xs2[idx] = (src[0] + src[1] + src[64] + src[65]) * 0.25f;
    } else {                         // s=4, h=16
        int idx = (bid - 2048) * 256 + threadIdx.x;
        int p = idx & 255;
        int bc = idx >> 8;
        int oy = p >> 4, ox = p & 15;
        const float* src = x + (bc << 12) + (oy * 4) * 64 + ox * 4;
        float s = 0.0f;
        #pragma unroll
        for (int dy = 0; dy < 4; ++dy)
            #pragma unroll
            for (int dx = 0; dx < 4; ++dx) s += src[dy * 64 + dx];
        xs4[idx] = s * 0.0625f;
    }
}

// ---------- GN stage 1: partial sums, all scales ----------
__device__ __forceinline__ void gn_part_body(const float* __restrict__ xs,
                                             float* __restrict__ part,
                                             int blk, int hwShift) {
    int sp = blk & (SPLIT - 1);
    int bg = blk >> 4;
    int b = bg >> 3, g = bg & 7;
    int count = CPG << hwShift;
    int chunk = count >> 4;
    const float* base = xs + ((b * C + g * CPG) << hwShift) + sp * chunk;
    float s = 0.0f, q = 0.0f;
    for (int i = threadIdx.x; i < chunk; i += 256) {
        float v = base[i];
        s += v; q += v * v;
    }
    __shared__ float rs[256], rq[256];
    rs[threadIdx.x] = s; rq[threadIdx.x] = q;
    __syncthreads();
    for (int st = 128; st > 0; st >>= 1) {
        if (threadIdx.x < st) {
            rs[threadIdx.x] += rs[threadIdx.x + st];
            rq[threadIdx.x] += rq[threadIdx.x + st];
        }
        __syncthreads();
    }
    if (threadIdx.x == 0) {
        part[blk * 2]     = rs[0];
        part[blk * 2 + 1] = rq[0];
    }
}

__global__ __launch_bounds__(256) void gn_part_all_kernel(const float* __restrict__ x,
                                                          const float* __restrict__ xs2,
                                                          const float* __restrict__ xs4,
                                                          float* __restrict__ part) {
    int bid = blockIdx.x;
    if (bid < 512)       gn_part_body(x,   part,          bid,        12);
    else if (bid < 1024) gn_part_body(xs2, part + 1024,   bid - 512,  10);
    else                 gn_part_body(xs4, part + 2048,   bid - 1024, 8);
}

// ---------- GN stage 2: fold -> per-(b,c) affine ----------
__global__ __launch_bounds__(256) void gn_final_all_kernel(const float* __restrict__ part,
                                                           const float* __restrict__ gn_w,
                                                           const float* __restrict__ gn_b,
                                                           float2* __restrict__ scsh) {
    int bid = blockIdx.x;              // 6 blocks: si = bid>>1
    int si = bid >> 1;
    int idx = (bid & 1) * 256 + threadIdx.x;     // 0..511 = b*C + c
    int c = idx & 127, b = idx >> 7;
    int bg = b * 8 + (c >> 4);
    const float* pp = part + si * 1024;
    float s = 0.0f, q = 0.0f;
    #pragma unroll
    for (int sp = 0; sp < SPLIT; ++sp) {
        s += pp[(bg * SPLIT + sp) * 2];
        q += pp[(bg * SPLIT + sp) * 2 + 1];
    }
    int hwShift = (si == 0) ? 12 : ((si == 1) ? 10 : 8);
    float inv = 1.0f / (float)(CPG << hwShift);
    float mu = s * inv;
    float var = q * inv - mu * mu;
    float rsig = rsqrtf(var + 1e-5f);
    float a = rsig * gn_w[si * C + c];
    float2 r; r.x = a; r.y = gn_b[si * C + c] - mu * a;
    scsh[si * 512 + idx] = r;
}

// ---------- QKV projection with fused GN -> bf16 ----------
template <int N, int NSH>
__device__ __forceinline__ void qkv_body(int bi, const float* __restrict__ xs,
    const float2* __restrict__ scsh,
    const float* __restrict__ qw, const float* __restrict__ qb,
    const float* __restrict__ kw, const float* __restrict__ kb,
    const float* __restrict__ vw, const float* __restrict__ vb,
    ushort_t* __restrict__ q_bf, ushort_t* __restrict__ k_bf, ushort_t* __restrict__ v_bf) {
    const int nc = N >> 8;
    int nchunk = bi % nc; bi /= nc;
    int og = bi & 3; bi >>= 2;
    int proj = bi % 3; int b = bi / 3;
    const float* wp = (proj == 0) ? qw : ((proj == 1) ? kw : vw);
    const float* bp = (proj == 0) ? qb : ((proj == 1) ? kb : vb);
    __shared__ float wl[8 * 128];
    __shared__ float2 ss[128];
    {
        int t = threadIdx.x;
        #pragma unroll
        for (int r = 0; r < 4; ++r) {
            int e = r * 256 + t;
            int o = e >> 7, c0 = e & 127;
            wl[c0 * 8 + o] = wp[(og * 8 + o) * C + c0];
        }
        if (t < 128) ss[t] = scsh[b * 128 + t];
    }
    __syncthreads();
    int n = nchunk * 256 + threadIdx.x;
    const float* xb = xs + ((size_t)(b * C) << NSH) + n;
    float acc[8];
    #pragma unroll
    for (int o = 0; o < 8; ++o) acc[o] = bp[og * 8 + o];
    #pragma unroll 2
    for (int c0 = 0; c0 < C; ++c0) {
        float raw = xb[(size_t)c0 << NSH];
        float2 s2 = ss[c0];
        float xv = fmaf(s2.x, raw, s2.y);
        const float4* wr = (const float4*)&wl[c0 * 8];
        float4 w0 = wr[0], w1 = wr[1];
        acc[0] += w0.x * xv; acc[1] += w0.y * xv; acc[2] += w0.z * xv; acc[3] += w0.w * xv;
        acc[4] += w1.x * xv; acc[5] += w1.y * xv; acc[6] += w1.z * xv; acc[7] += w1.w * xv;
    }
    if (proj < 2) {
        ushort_t tmp[8];
        #pragma unroll
        for (int o = 0; o < 8; ++o) tmp[o] = f2bf(acc[o]);
        ushort_t* dst = ((proj == 0) ? q_bf : k_bf) + ((size_t)(b * N + n)) * 32 + og * 8;
        *(uint4*)dst = *(const uint4*)tmp;
    } else {
        #pragma unroll
        for (int o = 0; o < 8; ++o)
            v_bf[((size_t)(b * 32 + og * 8 + o) << NSH) + n] = f2bf(acc[o]);
    }
}

__global__ __launch_bounds__(256) void qkv_all_kernel(const float* __restrict__ x,
    const float* __restrict__ xs2, const float* __restrict__ xs4,
    const float2* __restrict__ scsh,
    const float* __restrict__ qw, const float* __restrict__ qb,
    const float* __restrict__ kw, const float* __restrict__ kb,
    const float* __restrict__ vw, const float* __restrict__ vb,
    ushort_t* __restrict__ qbf, ushort_t* __restrict__ kbf, ushort_t* __restrict__ vbf) {
    int bid = blockIdx.x;
    if (bid < 768) {
        qkv_body<N1, 12>(bid, x, scsh, qw, qb, kw, kb, vw, vb, qbf, kbf, vbf);
    } else if (bid < 960) {
        qkv_body<N2, 10>(bid - 768, xs2, scsh + 512,
                         qw + INTER * C, qb + INTER, kw + INTER * C, kb + INTER,
                         vw + INTER * C, vb + INTER,
                         qbf + QOFF2, kbf + QOFF2, vbf + QOFF2);
    } else {
        qkv_body<N4, 8>(bid - 960, xs4, scsh + 1024,
                        qw + 2 * INTER * C, qb + 2 * INTER, kw + 2 * INTER * C, kb + 2 * INTER,
                        vw + 2 * INTER * C, vb + 2 * INTER,
                        qbf + QOFF4, kbf + QOFF4, vbf + QOFF4);
    }
}

// ---------- MFMA flash attention (split-K), all scales ----------
template <int N, int NSH>
__device__ __forceinline__ void attn_body(int bi,
    const ushort_t* __restrict__ q_bf, const ushort_t* __restrict__ k_bf,
    const ushort_t* __restrict__ v_bf,
    float* __restrict__ pacc, float* __restrict__ pml,
    ushort_t* K_lds, ushort_t* V_lds, ushort_t* P_lds) {
    int ks = bi % KS; bi /= KS;
    const int nqc = N >> 6;
    int qc = bi % nqc; int b = bi / nqc;
    int tid = threadIdx.x;
    int l = tid & 63, w = tid >> 6, lq = l & 15, g = l >> 4;
    int q0 = qc * 64 + w * 16;
    const float invs = 0.17677669529663687f;   // 1/sqrt(32)

    short8 qf = *(const short8*)(q_bf + ((size_t)(b * N + q0 + lq)) * 32 + g * 8);
    f32x4 acco0 = {0.f, 0.f, 0.f, 0.f}, acco1 = {0.f, 0.f, 0.f, 0.f};
    float mrun = -3.0e38f, lrun = 0.0f;

    const int kchunk = N / KS;
    int kbase = ks * kchunk;
    const int ntiles = kchunk >> 6;
    ushort_t* Pw = P_lds + w * 16 * 72;

    for (int t = 0; t < ntiles; ++t) {
        int kt0 = kbase + t * 64;
        __syncthreads();
        {
            const uint4* ksrc = (const uint4*)(k_bf + ((size_t)(b * N + kt0 + (tid >> 2))) * 32 + (tid & 3) * 8);
            *(uint4*)&K_lds[(tid >> 2) * 40 + (tid & 3) * 8] = *ksrc;
            const uint4* vsrc = (const uint4*)(v_bf + (((size_t)(b * 32 + (tid >> 3))) << NSH) + kt0 + (tid & 7) * 8);
            *(uint4*)&V_lds[(tid >> 3) * 72 + (tid & 7) * 8] = *vsrc;
        }
        __syncthreads();

        f32x4 sa[4];
        #pragma unroll
        for (int kt = 0; kt < 4; ++kt) {
            short8 kf = *(const short8*)&K_lds[(kt * 16 + lq) * 40 + g * 8];
            f32x4 z = {0.f, 0.f, 0.f, 0.f};
            sa[kt] = __builtin_amdgcn_mfma_f32_16x16x32_bf16(kf, qf, z, 0, 0, 0);
        }
        float sc[16];
        #pragma unroll
        for (int kt = 0; kt < 4; ++kt) {
            sc[kt * 4 + 0] = sa[kt][0] * invs;
            sc[kt * 4 + 1] = sa[kt][1] * invs;
            sc[kt * 4 + 2] = sa[kt][2] * invs;
            sc[kt * 4 + 3] = sa[kt][3] * invs;
        }
        float tmax = sc[0];
        #pragma unroll
        for (int j = 1; j < 16; ++j) tmax = fmaxf(tmax, sc[j]);
        tmax = fmaxf(tmax, __shfl_xor(tmax, 16, 64));
        tmax = fmaxf(tmax, __shfl_xor(tmax, 32, 64));
        float nm = fmaxf(mrun, tmax);
        float corr = __expf(mrun - nm);
        float psum = 0.0f;
        ushort_t pb[16];
        #pragma unroll
        for (int j = 0; j < 16; ++j) {
            float p = __expf(sc[j] - nm);
            psum += p;
            pb[j] = f2bf(p);
        }
        psum += __shfl_xor(psum, 16, 64);
        psum += __shfl_xor(psum, 32, 64);
        lrun = lrun * corr + psum;
        mrun = nm;
        #pragma unroll
        for (int e = 0; e < 4; ++e) { acco0[e] *= corr; acco1[e] *= corr; }
        #pragma unroll
        for (int kt = 0; kt < 4; ++kt) {
            short4v pv4;
            pv4[0] = (short)pb[kt * 4 + 0];
            pv4[1] = (short)pb[kt * 4 + 1];
            pv4[2] = (short)pb[kt * 4 + 2];
            pv4[3] = (short)pb[kt * 4 + 3];
            *(short4v*)&Pw[lq * 72 + kt * 16 + g * 4] = pv4;
        }
        #pragma unroll
        for (int c = 0; c < 2; ++c) {
            short8 pf  = *(const short8*)&Pw[lq * 72 + c * 32 + g * 8];
            short8 vf0 = *(const short8*)&V_lds[(lq) * 72 + c * 32 + g * 8];
            short8 vf1 = *(const short8*)&V_lds[(16 + lq) * 72 + c * 32 + g * 8];
            acco0 = __builtin_amdgcn_mfma_f32_16x16x32_bf16(vf0, pf, acco0, 0, 0, 0);
            acco1 = __builtin_amdgcn_mfma_f32_16x16x32_bf16(vf1, pf, acco1, 0, 0, 0);
        }
    }
    int n = q0 + lq;
    size_t pb_ = ((size_t)(b * KS + ks)) * 32;
    #pragma unroll
    for (int r = 0; r < 4; ++r) {
        pacc[(pb_ + (g * 4 + r)) * N + n]      = acco0[r];
        pacc[(pb_ + 16 + (g * 4 + r)) * N + n] = acco1[r];
    }
    if (g == 0) {
        pml[((size_t)(b * KS + ks) * 2) * N + n]     = mrun;
        pml[((size_t)(b * KS + ks) * 2 + 1) * N + n] = lrun;
    }
}

__global__ __launch_bounds__(256) void attn_all_kernel(
    const ushort_t* __restrict__ qbf, const ushort_t* __restrict__ kbf,
    const ushort_t* __restrict__ vbf,
    float* __restrict__ pacc, float* __restrict__ pml) {
    __shared__ ushort_t K_lds[64 * 40];
    __shared__ ushort_t V_lds[32 * 72];
    __shared__ ushort_t P_lds[4 * 16 * 72];
    int bid = blockIdx.x;
    if (bid < 1024) {
        attn_body<N1, 12>(bid, qbf, kbf, vbf, pacc, pml, K_lds, V_lds, P_lds);
    } else if (bid < 1280) {
        attn_body<N2, 10>(bid - 1024, qbf + QOFF2, kbf + QOFF2, vbf + QOFF2,
                          pacc + PAOFF2, pml + PMOFF2, K_lds, V_lds, P_lds);
    } else {
        attn_body<N4, 8>(bid - 1280, qbf + QOFF4, kbf + QOFF4, vbf + QOFF4,
                         pacc + PAOFF4, pml + PMOFF4, K_lds, V_lds, P_lds);
    }
}

// ---------- combine split-K -> att ----------
template <int N, int NSH>
__device__ __forceinline__ void combine_body(int idx, const float* __restrict__ pacc,
                                             const float* __restrict__ pml,
                                             float* __restrict__ att) {
    int n = idx & (N - 1);
    int o = (idx >> NSH) & 31;
    int b = idx >> (NSH + 5);
    float mv[KS];
    float M = -3.0e38f;
    #pragma unroll
    for (int ks = 0; ks < KS; ++ks) {
        mv[ks] = pml[((size_t)(b * KS + ks) * 2) * N + n];
        M = fmaxf(M, mv[ks]);
    }
    float L = 0.0f, a = 0.0f;
    #pragma unroll
    for (int ks = 0; ks < KS; ++ks) {
        float wgt = __expf(mv[ks] - M);
        L += pml[((size_t)(b * KS + ks) * 2 + 1) * N + n] * wgt;
        a += pacc[((size_t)(b * KS + ks) * INTER + o) * N + n] * wgt;
    }
    att[((size_t)(b * INTER + o) << NSH) + n] = a / L;
}

__global__ __launch_bounds__(256) void combine_all_kernel(const float* __restrict__ pacc,
                                                          const float* __restrict__ pml,
                                                          float* __restrict__ att) {
    int bid = blockIdx.x;
    int idx = bid * 256 + threadIdx.x;
    if (bid < 2048)      combine_body<N1, 12>(idx, pacc, pml, att);
    else if (bid < 2560) combine_body<N2, 10>(idx - 524288, pacc + PAOFF2, pml + PMOFF2, att + QOFF2);
    else                 combine_body<N4, 8>(idx - 655360, pacc + PAOFF4, pml + PMOFF4, att + QOFF4);
}

// ---------- output projection + residual (+ w0 scaling for s=1) ----------
template <int N, int NSH>
__device__ __forceinline__ void oy_body(int idx, const float* __restrict__ att,
                                        const float* __restrict__ ow,
                                        const float* __restrict__ ob,
                                        const float* __restrict__ gamma,
                                        const float* __restrict__ xs,
                                        float* __restrict__ ydst,
                                        const float* __restrict__ sw) {
    int n = idx & (N - 1);
    int c = (idx >> NSH) & (C - 1);
    int b = idx >> (NSH + 7);
    float acc = ob[c];
    const float* ab = att + ((size_t)(b * INTER) << NSH) + n;
    #pragma unroll
    for (int i = 0; i < INTER; ++i) acc += ow[c * INTER + i] * ab[i << NSH];
    float y = gamma[0] * acc + xs[idx];
    if (sw) {
        float w0, w1, w2; scale_wts(sw, w0, w1, w2);
        ydst[idx] = w0 * y;
    } else {
        ydst[idx] = y;
    }
}

__global__ __launch_bounds__(256) void oy_all_kernel(const float* __restrict__ att,
    const float* __restrict__ ow, const float* __restrict__ ob,
    const float* __restrict__ gamma,
    const float* __restrict__ x, const float* __restrict__ xs2, const float* __restrict__ xs4,
    float* __restrict__ out, float* __restrict__ y2, float* __restrict__ y4,
    const float* __restrict__ sw) {
    int bid = blockIdx.x;
    int idx = bid * 256 + threadIdx.x;
    if (bid < 8192) {
        oy_body<N1, 12>(idx, att, ow, ob, gamma, x, out, sw);
    } else if (bid < 10240) {
        oy_body<N2, 10>(idx - 2097152, att + QOFF2, ow + C * INTER, ob + C, gamma + 1,
                        xs2, y2, nullptr);
    } else {
        oy_body<N4, 8>(idx - 2621440, att + QOFF4, ow + 2 * C * INTER, ob + 2 * C, gamma + 2,
                       xs4, y4, nullptr);
    }
}

// ---------- bilinear upsample + weighted fuse ----------
__device__ __forceinline__ float bilerp(const float* __restrict__ img, int in,
                                        int oy, int ox, float r) {
    float cy = (oy + 0.5f) * r - 0.5f;
    cy = fminf(fmaxf(cy, 0.0f), (float)(in - 1));
    float cx = (ox + 0.5f) * r - 0.5f;
    cx = fminf(fmaxf(cx, 0.0f), (float)(in - 1));
    int y0 = (int)cy; int y1i = (y0 + 1 < in) ? y0 + 1 : in - 1; float ty = cy - (float)y0;
    int x0 = (int)cx; int x1i = (x0 + 1 < in) ? x0 + 1 : in - 1; float tx = cx - (float)x0;
    float v00 = img[y0 * in + x0];
    float v01 = img[y0 * in + x1i];
    float v10 = img[y1i * in + x0];
    float v11 = img[y1i * in + x1i];
    float top = v00 * (1.0f - tx) + v01 * tx;
    float bot = v10 * (1.0f - tx) + v11 * tx;
    return top * (1.0f - ty) + bot * ty;
}

__global__ __launch_bounds__(256) void fuse_kernel(float* __restrict__ out,
                                                   const float* __restrict__ y2,
                                                   const float* __restrict__ y4,
                                                   const float* __restrict__ sw) {
    int idx = blockIdx.x * 256 + threadIdx.x;
    int p = idx & 4095;
    int bc = idx >> 12;
    int oy = p >> 6, ox = p & 63;
    float w0, w1, w2; scale_wts(sw, w0, w1, w2);
    float v2 = bilerp(y2 + bc * 1024, 32, oy, ox, 0.5f);
    float v4 = bilerp(y4 + bc * 256, 16, oy, ox, 0.25f);
    out[idx] = out[idx] + w1 * v2 + w2 * v4;
}

extern "C" void kernel_launch(void* const* d_in, const int* in_sizes, int n_in,
                              void* d_out, int out_size, void* d_ws, size_t ws_size,
                              hipStream_t stream) {
    const float* x     = (const float*)d_in[0];
    const float* gn_w  = (const float*)d_in[1];
    const float* gn_b  = (const float*)d_in[2];
    const float* qw    = (const float*)d_in[3];
    const float* qb    = (const float*)d_in[4];
    const float* kw    = (const float*)d_in[5];
    const float* kb    = (const float*)d_in[6];
    const float* vw    = (const float*)d_in[7];
    const float* vb    = (const float*)d_in[8];
    const float* ow    = (const float*)d_in[9];
    const float* ob    = (const float*)d_in[10];
    const float* gamma = (const float*)d_in[11];
    const float* sw    = (const float*)d_in[12];
    float* out = (float*)d_out;

    float* ws    = (float*)d_ws;
    float* xs2   = ws;                         // 524288
    float* xs4   = xs2 + 524288;               // 131072
    float* attb  = xs4 + 131072;               // QTOT = 688128
    float* y2    = attb + QTOT;                // 524288
    float* y4    = y2 + 524288;                // 131072
    float* part  = y4 + 131072;                // 3072
    float* scshf = part + 3072;                // 3072
    float* pacc  = scshf + 3072;               // PATOT = 2752512
    float* pml   = pacc + PATOT;               // PMTOT = 172032
    ushort_t* qbf = (ushort_t*)(pml + PMTOT);  // QTOT ushorts each
    ushort_t* kbf = qbf + QTOT;
    ushort_t* vbf = kbf + QTOT;
    float2* scsh = (float2*)scshf;

    avgpool_all_kernel<<<2560, 256, 0, stream>>>(x, xs2, xs4);
    gn_part_all_kernel<<<1536, 256, 0, stream>>>(x, xs2, xs4, part);
    gn_final_all_kernel<<<6, 256, 0, stream>>>(part, gn_w, gn_b, scsh);
    qkv_all_kernel<<<1008, 256, 0, stream>>>(x, xs2, xs4, scsh,
                                             qw, qb, kw, kb, vw, vb, qbf, kbf, vbf);
    attn_all_kernel<<<1344, 256, 0, stream>>>(qbf, kbf, vbf, pacc, pml);
    combine_all_kernel<<<2688, 256, 0, stream>>>(pacc, pml, attb);
    oy_all_kernel<<<10752, 256, 0, stream>>>(attb, ow, ob, gamma, x, xs2, xs4,
                                             out, y2, y4, sw);
    fuse_kernel<<<8192, 256, 0, stream>>>(out, y2, y4, sw);
}

// Round 6
// 81.756 us; speedup vs baseline: 27.1131x; 1.2854x over previous
//
#include <hip/hip_runtime.h>
#include <math.h>

#define B 4
#define C 128
#define G 8
#define CPG 16
#define INTER 32
#define SPLIT 16
#define KS 4

#define N1 4096
#define N2 1024
#define N4 256

// element offsets (compile-time)
#define QOFF2 (B * N1 * 32)                  // 524288
#define QOFF4 (QOFF2 + B * N2 * 32)          // 655360
#define QTOT  (QOFF4 + B * N4 * 32)          // 688128
#define PAOFF2 (B * KS * 32 * N1)            // 2097152
#define PAOFF4 (PAOFF2 + B * KS * 32 * N2)   // 2621440
#define PATOT  (PAOFF4 + B * KS * 32 * N4)   // 2752512
#define PMOFF2 (B * KS * 2 * N1)             // 131072
#define PMOFF4 (PMOFF2 + B * KS * 2 * N2)    // 163840
#define PMTOT  (PMOFF4 + B * KS * 2 * N4)    // 172032

typedef unsigned short ushort_t;
typedef __attribute__((ext_vector_type(8))) short short8;
typedef __attribute__((ext_vector_type(4))) short short4v;
typedef __attribute__((ext_vector_type(4))) float f32x4;

__device__ __forceinline__ ushort_t f2bf(float f) {
    union { float f; unsigned u; } x; x.f = f;
    unsigned r = x.u + 0x7fffu + ((x.u >> 16) & 1u);
    return (ushort_t)(r >> 16);
}

__device__ __forceinline__ void scale_wts(const float* __restrict__ sw,
                                          float& w0, float& w1, float& w2) {
    float a = sw[0], b = sw[1], c = sw[2];
    float m = fmaxf(a, fmaxf(b, c));
    float e0 = __expf(a - m), e1 = __expf(b - m), e2 = __expf(c - m);
    float inv = 1.0f / (e0 + e1 + e2);
    w0 = e0 * inv; w1 = e1 * inv; w2 = e2 * inv;
}

__device__ __forceinline__ void block_reduce_write(float s, float q,
                                                   float* __restrict__ dst2) {
    __shared__ float rs[256], rq[256];
    rs[threadIdx.x] = s; rq[threadIdx.x] = q;
    __syncthreads();
    for (int st = 128; st > 0; st >>= 1) {
        if (threadIdx.x < st) {
            rs[threadIdx.x] += rs[threadIdx.x + st];
            rq[threadIdx.x] += rq[threadIdx.x + st];
        }
        __syncthreads();
    }
    if (threadIdx.x == 0) { dst2[0] = rs[0]; dst2[1] = rq[0]; }
}

// ---------- kernel 1: avgpool (s=2,4) fused with GN partial sums (all scales) ----------
__global__ __launch_bounds__(256) void pool_stats_kernel(const float* __restrict__ x,
                                                         float* __restrict__ xs2,
                                                         float* __restrict__ xs4,
                                                         float* __restrict__ part) {
    int bid = blockIdx.x;
    if (bid < 512) {
        // s=1 stats on x: (bg, sp) chunks of 4096
        int sp = bid & 15, bg = bid >> 4;
        const float* base = x + ((bg * CPG) << 12) + sp * 4096;
        float s = 0.0f, q = 0.0f;
        for (int i = threadIdx.x; i < 4096; i += 256) {
            float v = base[i];
            s += v; q += v * v;
        }
        block_reduce_write(s, q, part + bid * 2);
    } else if (bid < 1024) {
        // s=2: one channel plane per block: pool 64x64 -> 32x32 + stats
        int blk = bid - 512;
        int sp = blk & 15, bg = blk >> 4;
        int bc = bg * CPG + sp;            // == b*C + c
        const float* src = x + (bc << 12);
        float* dst = xs2 + (bc << 10);
        float s = 0.0f, q = 0.0f;
        for (int p = threadIdx.x; p < 1024; p += 256) {
            int oy = p >> 5, ox = p & 31;
            const float* s2 = src + oy * 128 + ox * 2;
            float v = (s2[0] + s2[1] + s2[64] + s2[65]) * 0.25f;
            dst[p] = v; s += v; q += v * v;
        }
        block_reduce_write(s, q, part + 1024 + blk * 2);
    } else {
        // s=4: one channel plane per block: pool 64x64 -> 16x16 + stats
        int blk = bid - 1024;
        int sp = blk & 15, bg = blk >> 4;
        int bc = bg * CPG + sp;
        const float* src = x + (bc << 12);
        float* dst = xs4 + (bc << 8);
        float s = 0.0f, q = 0.0f;
        if (threadIdx.x < 256) {
            int p = threadIdx.x;
            int oy = p >> 4, ox = p & 15;
            const float* s4 = src + oy * 256 + ox * 4;
            float v = 0.0f;
            #pragma unroll
            for (int dy = 0; dy < 4; ++dy)
                #pragma unroll
                for (int dx = 0; dx < 4; ++dx) v += s4[dy * 64 + dx];
            v *= 0.0625f;
            dst[p] = v; s = v; q = v * v;
        }
        block_reduce_write(s, q, part + 2048 + blk * 2);
    }
}

// ---------- kernel 2: QKV projection with inline GN fold -> bf16 ----------
template <int N, int NSH>
__device__ __forceinline__ void qkv_body(int bi, const float* __restrict__ xs,
    const float* __restrict__ part,
    const float* __restrict__ gn_w, const float* __restrict__ gn_b,
    const float* __restrict__ qw, const float* __restrict__ qb,
    const float* __restrict__ kw, const float* __restrict__ kb,
    const float* __restrict__ vw, const float* __restrict__ vb,
    ushort_t* __restrict__ q_bf, ushort_t* __restrict__ k_bf, ushort_t* __restrict__ v_bf) {
    const int nc = N >> 8;
    int nchunk = bi % nc; bi /= nc;
    int og = bi & 3; bi >>= 2;
    int proj = bi % 3; int b = bi / 3;
    const float* wp = (proj == 0) ? qw : ((proj == 1) ? kw : vw);
    const float* bp = (proj == 0) ? qb : ((proj == 1) ? kb : vb);
    __shared__ float wl[8 * 128];
    __shared__ float2 ss[128];
    {
        int t = threadIdx.x;
        #pragma unroll
        for (int r = 0; r < 4; ++r) {
            int e = r * 256 + t;
            int o = e >> 7, c0 = e & 127;
            wl[c0 * 8 + o] = wp[(og * 8 + o) * C + c0];
        }
        if (t < 128) {
            int c = t;
            int bg = b * 8 + (c >> 4);
            float s = 0.0f, q = 0.0f;
            #pragma unroll
            for (int sp = 0; sp < SPLIT; ++sp) {
                s += part[(bg * SPLIT + sp) * 2];
                q += part[(bg * SPLIT + sp) * 2 + 1];
            }
            float inv = 1.0f / (float)(CPG << NSH);
            float mu = s * inv;
            float var = q * inv - mu * mu;
            float rsig = rsqrtf(var + 1e-5f);
            float a = rsig * gn_w[c];
            float2 r; r.x = a; r.y = gn_b[c] - mu * a;
            ss[c] = r;
        }
    }
    __syncthreads();
    int n = nchunk * 256 + threadIdx.x;
    const float* xb = xs + ((size_t)(b * C) << NSH) + n;
    float acc[8];
    #pragma unroll
    for (int o = 0; o < 8; ++o) acc[o] = bp[og * 8 + o];
    #pragma unroll 2
    for (int c0 = 0; c0 < C; ++c0) {
        float raw = xb[(size_t)c0 << NSH];
        float2 s2 = ss[c0];
        float xv = fmaf(s2.x, raw, s2.y);
        const float4* wr = (const float4*)&wl[c0 * 8];
        float4 w0 = wr[0], w1 = wr[1];
        acc[0] += w0.x * xv; acc[1] += w0.y * xv; acc[2] += w0.z * xv; acc[3] += w0.w * xv;
        acc[4] += w1.x * xv; acc[5] += w1.y * xv; acc[6] += w1.z * xv; acc[7] += w1.w * xv;
    }
    if (proj < 2) {
        ushort_t tmp[8];
        #pragma unroll
        for (int o = 0; o < 8; ++o) tmp[o] = f2bf(acc[o]);
        ushort_t* dst = ((proj == 0) ? q_bf : k_bf) + ((size_t)(b * N + n)) * 32 + og * 8;
        *(uint4*)dst = *(const uint4*)tmp;
    } else {
        #pragma unroll
        for (int o = 0; o < 8; ++o)
            v_bf[((size_t)(b * 32 + og * 8 + o) << NSH) + n] = f2bf(acc[o]);
    }
}

__global__ __launch_bounds__(256) void qkv_all_kernel(const float* __restrict__ x,
    const float* __restrict__ xs2, const float* __restrict__ xs4,
    const float* __restrict__ part,
    const float* __restrict__ gn_w, const float* __restrict__ gn_b,
    const float* __restrict__ qw, const float* __restrict__ qb,
    const float* __restrict__ kw, const float* __restrict__ kb,
    const float* __restrict__ vw, const float* __restrict__ vb,
    ushort_t* __restrict__ qbf, ushort_t* __restrict__ kbf, ushort_t* __restrict__ vbf) {
    int bid = blockIdx.x;
    if (bid < 768) {
        qkv_body<N1, 12>(bid, x, part, gn_w, gn_b, qw, qb, kw, kb, vw, vb, qbf, kbf, vbf);
    } else if (bid < 960) {
        qkv_body<N2, 10>(bid - 768, xs2, part + 1024, gn_w + C, gn_b + C,
                         qw + INTER * C, qb + INTER, kw + INTER * C, kb + INTER,
                         vw + INTER * C, vb + INTER,
                         qbf + QOFF2, kbf + QOFF2, vbf + QOFF2);
    } else {
        qkv_body<N4, 8>(bid - 960, xs4, part + 2048, gn_w + 2 * C, gn_b + 2 * C,
                        qw + 2 * INTER * C, qb + 2 * INTER, kw + 2 * INTER * C, kb + 2 * INTER,
                        vw + 2 * INTER * C, vb + 2 * INTER,
                        qbf + QOFF4, kbf + QOFF4, vbf + QOFF4);
    }
}

// ---------- kernel 3: MFMA flash attention (split-K), all scales ----------
template <int N, int NSH>
__device__ __forceinline__ void attn_body(int bi,
    const ushort_t* __restrict__ q_bf, const ushort_t* __restrict__ k_bf,
    const ushort_t* __restrict__ v_bf,
    float* __restrict__ pacc, float* __restrict__ pml,
    ushort_t* K_lds, ushort_t* V_lds, ushort_t* P_lds) {
    int ks = bi % KS; bi /= KS;
    const int nqc = N >> 6;
    int qc = bi % nqc; int b = bi / nqc;
    int tid = threadIdx.x;
    int l = tid & 63, w = tid >> 6, lq = l & 15, g = l >> 4;
    int q0 = qc * 64 + w * 16;
    const float invs = 0.17677669529663687f;   // 1/sqrt(32)

    short8 qf = *(const short8*)(q_bf + ((size_t)(b * N + q0 + lq)) * 32 + g * 8);
    f32x4 acco0 = {0.f, 0.f, 0.f, 0.f}, acco1 = {0.f, 0.f, 0.f, 0.f};
    float mrun = -3.0e38f, lrun = 0.0f;

    const int kchunk = N / KS;
    int kbase = ks * kchunk;
    const int ntiles = kchunk >> 6;
    ushort_t* Pw = P_lds + w * 16 * 72;

    for (int t = 0; t < ntiles; ++t) {
        int kt0 = kbase + t * 64;
        __syncthreads();
        {
            const uint4* ksrc = (const uint4*)(k_bf + ((size_t)(b * N + kt0 + (tid >> 2))) * 32 + (tid & 3) * 8);
            *(uint4*)&K_lds[(tid >> 2) * 40 + (tid & 3) * 8] = *ksrc;
            const uint4* vsrc = (const uint4*)(v_bf + (((size_t)(b * 32 + (tid >> 3))) << NSH) + kt0 + (tid & 7) * 8);
            *(uint4*)&V_lds[(tid >> 3) * 72 + (tid & 7) * 8] = *vsrc;
        }
        __syncthreads();

        f32x4 sa[4];
        #pragma unroll
        for (int kt = 0; kt < 4; ++kt) {
            short8 kf = *(const short8*)&K_lds[(kt * 16 + lq) * 40 + g * 8];
            f32x4 z = {0.f, 0.f, 0.f, 0.f};
            sa[kt] = __builtin_amdgcn_mfma_f32_16x16x32_bf16(kf, qf, z, 0, 0, 0);
        }
        float sc[16];
        #pragma unroll
        for (int kt = 0; kt < 4; ++kt) {
            sc[kt * 4 + 0] = sa[kt][0] * invs;
            sc[kt * 4 + 1] = sa[kt][1] * invs;
            sc[kt * 4 + 2] = sa[kt][2] * invs;
            sc[kt * 4 + 3] = sa[kt][3] * invs;
        }
        float tmax = sc[0];
        #pragma unroll
        for (int j = 1; j < 16; ++j) tmax = fmaxf(tmax, sc[j]);
        tmax = fmaxf(tmax, __shfl_xor(tmax, 16, 64));
        tmax = fmaxf(tmax, __shfl_xor(tmax, 32, 64));
        float nm = fmaxf(mrun, tmax);
        float corr = __expf(mrun - nm);
        float psum = 0.0f;
        ushort_t pb[16];
        #pragma unroll
        for (int j = 0; j < 16; ++j) {
            float p = __expf(sc[j] - nm);
            psum += p;
            pb[j] = f2bf(p);
        }
        psum += __shfl_xor(psum, 16, 64);
        psum += __shfl_xor(psum, 32, 64);
        lrun = lrun * corr + psum;
        mrun = nm;
        #pragma unroll
        for (int e = 0; e < 4; ++e) { acco0[e] *= corr; acco1[e] *= corr; }
        #pragma unroll
        for (int kt = 0; kt < 4; ++kt) {
            short4v pv4;
            pv4[0] = (short)pb[kt * 4 + 0];
            pv4[1] = (short)pb[kt * 4 + 1];
            pv4[2] = (short)pb[kt * 4 + 2];
            pv4[3] = (short)pb[kt * 4 + 3];
            *(short4v*)&Pw[lq * 72 + kt * 16 + g * 4] = pv4;
        }
        #pragma unroll
        for (int c = 0; c < 2; ++c) {
            short8 pf  = *(const short8*)&Pw[lq * 72 + c * 32 + g * 8];
            short8 vf0 = *(const short8*)&V_lds[(lq) * 72 + c * 32 + g * 8];
            short8 vf1 = *(const short8*)&V_lds[(16 + lq) * 72 + c * 32 + g * 8];
            acco0 = __builtin_amdgcn_mfma_f32_16x16x32_bf16(vf0, pf, acco0, 0, 0, 0);
            acco1 = __builtin_amdgcn_mfma_f32_16x16x32_bf16(vf1, pf, acco1, 0, 0, 0);
        }
    }
    int n = q0 + lq;
    size_t pb_ = ((size_t)(b * KS + ks)) * 32;
    #pragma unroll
    for (int r = 0; r < 4; ++r) {
        pacc[(pb_ + (g * 4 + r)) * N + n]      = acco0[r];
        pacc[(pb_ + 16 + (g * 4 + r)) * N + n] = acco1[r];
    }
    if (g == 0) {
        pml[((size_t)(b * KS + ks) * 2) * N + n]     = mrun;
        pml[((size_t)(b * KS + ks) * 2 + 1) * N + n] = lrun;
    }
}

__global__ __launch_bounds__(256) void attn_all_kernel(
    const ushort_t* __restrict__ qbf, const ushort_t* __restrict__ kbf,
    const ushort_t* __restrict__ vbf,
    float* __restrict__ pacc, float* __restrict__ pml) {
    __shared__ ushort_t K_lds[64 * 40];
    __shared__ ushort_t V_lds[32 * 72];
    __shared__ ushort_t P_lds[4 * 16 * 72];
    int bid = blockIdx.x;
    if (bid < 1024) {
        attn_body<N1, 12>(bid, qbf, kbf, vbf, pacc, pml, K_lds, V_lds, P_lds);
    } else if (bid < 1280) {
        attn_body<N2, 10>(bid - 1024, qbf + QOFF2, kbf + QOFF2, vbf + QOFF2,
                          pacc + PAOFF2, pml + PMOFF2, K_lds, V_lds, P_lds);
    } else {
        attn_body<N4, 8>(bid - 1280, qbf + QOFF4, kbf + QOFF4, vbf + QOFF4,
                         pacc + PAOFF4, pml + PMOFF4, K_lds, V_lds, P_lds);
    }
}

// ---------- kernel 4: split-K combine + output projection + residual, fused ----------
// One block per (b, 32-column tile). Stage A: combine -> att tile in LDS.
// Stage B: o = ow@att + ob; y = gamma*o + xs; (optional w0 scaling).
template <int N, int NSH>
__device__ __forceinline__ void comb_oy_body(int tile, const float* __restrict__ pacc,
                                             const float* __restrict__ pml,
                                             const float* __restrict__ ow,
                                             const float* __restrict__ ob,
                                             const float* __restrict__ gamma,
                                             const float* __restrict__ xs,
                                             float* __restrict__ ydst,
                                             const float* __restrict__ sw,
                                             float* att_lds, float* ow_lds) {
    const int ntiles = N >> 5;
    int b = tile / ntiles;
    int n0 = (tile % ntiles) << 5;
    int t = threadIdx.x;
    // load ow into LDS (128x32 f32)
    {
        const float4* src = (const float4*)ow;
        float4* dst = (float4*)ow_lds;
        dst[t] = src[t];
        dst[256 + t] = src[256 + t];
        dst[512 + t] = src[512 + t];
        dst[768 + t] = src[768 + t];
    }
    // Stage A: combine 32 o x 32 n into att_lds (row stride 36)
    {
        int o = t >> 3, j = t & 3, half = (t >> 2) & 1;  // 32 o x 8 j-quads? remap:
        // simpler: o = t>>3 (0..31), j = t&7 -> 4 n each
        o = t >> 3; j = t & 7;
        int n = n0 + j * 4;
        float4 mv[KS], lv[KS], av[KS];
        float4 M = {-3.0e38f, -3.0e38f, -3.0e38f, -3.0e38f};
        #pragma unroll
        for (int ks = 0; ks < KS; ++ks) {
            mv[ks] = *(const float4*)&pml[((size_t)(b * KS + ks) * 2) * N + n];
            lv[ks] = *(const float4*)&pml[((size_t)(b * KS + ks) * 2 + 1) * N + n];
            av[ks] = *(const float4*)&pacc[((size_t)(b * KS + ks) * INTER + o) * N + n];
            M.x = fmaxf(M.x, mv[ks].x); M.y = fmaxf(M.y, mv[ks].y);
            M.z = fmaxf(M.z, mv[ks].z); M.w = fmaxf(M.w, mv[ks].w);
        }
        float4 L = {0.f, 0.f, 0.f, 0.f}, A = {0.f, 0.f, 0.f, 0.f};
        #pragma unroll
        for (int ks = 0; ks < KS; ++ks) {
            float4 wgt;
            wgt.x = __expf(mv[ks].x - M.x); wgt.y = __expf(mv[ks].y - M.y);
            wgt.z = __expf(mv[ks].z - M.z); wgt.w = __expf(mv[ks].w - M.w);
            L.x += lv[ks].x * wgt.x; L.y += lv[ks].y * wgt.y;
            L.z += lv[ks].z * wgt.z; L.w += lv[ks].w * wgt.w;
            A.x += av[ks].x * wgt.x; A.y += av[ks].y * wgt.y;
            A.z += av[ks].z * wgt.z; A.w += av[ks].w * wgt.w;
        }
        float4 r;
        r.x = A.x / L.x; r.y = A.y / L.y; r.z = A.z / L.z; r.w = A.w / L.w;
        *(float4*)&att_lds[o * 36 + j * 4] = r;
    }
    __syncthreads();
    // Stage B: 128 c x 32 n outputs; thread handles 16 c for one n.
    {
        int n = t & 31;
        int cg = t >> 5;                 // 0..7 -> c base = cg*16
        float av[INTER];
        #pragma unroll
        for (int i = 0; i < INTER; ++i) av[i] = att_lds[i * 36 + n];
        float gm = gamma[0];
        float wsc = 1.0f;
        bool scale = (sw != nullptr);
        if (scale) { float w0, w1, w2; scale_wts(sw, w0, w1, w2); wsc = w0; }
        const float* xsb = xs + ((size_t)(b * C + cg * 16) << NSH) + n0 + n;
        float* yb = ydst + ((size_t)(b * C + cg * 16) << NSH) + n0 + n;
        #pragma unroll
        for (int cc = 0; cc < 16; ++cc) {
            int c = cg * 16 + cc;
            const float4* wr = (const float4*)&ow_lds[c * 32];
            float a0 = 0.f, a1 = 0.f, a2 = 0.f, a3 = 0.f;
            #pragma unroll
            for (int i4 = 0; i4 < 8; ++i4) {
                float4 wv = wr[i4];
                a0 += wv.x * av[i4 * 4 + 0];
                a1 += wv.y * av[i4 * 4 + 1];
                a2 += wv.z * av[i4 * 4 + 2];
                a3 += wv.w * av[i4 * 4 + 3];
            }
            float o = ob[c] + ((a0 + a1) + (a2 + a3));
            float y = gm * o + xsb[(size_t)cc << NSH];
            yb[(size_t)cc << NSH] = wsc * y;
        }
    }
}

__global__ __launch_bounds__(256) void comb_oy_all_kernel(const float* __restrict__ pacc,
    const float* __restrict__ pml,
    const float* __restrict__ ow, const float* __restrict__ ob,
    const float* __restrict__ gamma,
    const float* __restrict__ x, const float* __restrict__ xs2, const float* __restrict__ xs4,
    float* __restrict__ out, float* __restrict__ y2, float* __restrict__ y4,
    const float* __restrict__ sw) {
    __shared__ float att_lds[32 * 36];
    __shared__ float ow_lds[128 * 32];
    int bid = blockIdx.x;
    if (bid < 512) {
        comb_oy_body<N1, 12>(bid, pacc, pml, ow, ob, gamma, x, out, sw, att_lds, ow_lds);
    } else if (bid < 640) {
        comb_oy_body<N2, 10>(bid - 512, pacc + PAOFF2, pml + PMOFF2,
                             ow + C * INTER, ob + C, gamma + 1, xs2, y2, nullptr,
                             att_lds, ow_lds);
    } else {
        comb_oy_body<N4, 8>(bid - 640, pacc + PAOFF4, pml + PMOFF4,
                            ow + 2 * C * INTER, ob + 2 * C, gamma + 2, xs4, y4, nullptr,
                            att_lds, ow_lds);
    }
}

// ---------- kernel 5: bilinear upsample + weighted fuse ----------
__device__ __forceinline__ float bilerp(const float* __restrict__ img, int in,
                                        int oy, int ox, float r) {
    float cy = (oy + 0.5f) * r - 0.5f;
    cy = fminf(fmaxf(cy, 0.0f), (float)(in - 1));
    float cx = (ox + 0.5f) * r - 0.5f;
    cx = fminf(fmaxf(cx, 0.0f), (float)(in - 1));
    int y0 = (int)cy; int y1i = (y0 + 1 < in) ? y0 + 1 : in - 1; float ty = cy - (float)y0;
    int x0 = (int)cx; int x1i = (x0 + 1 < in) ? x0 + 1 : in - 1; float tx = cx - (float)x0;
    float v00 = img[y0 * in + x0];
    float v01 = img[y0 * in + x1i];
    float v10 = img[y1i * in + x0];
    float v11 = img[y1i * in + x1i];
    float top = v00 * (1.0f - tx) + v01 * tx;
    float bot = v10 * (1.0f - tx) + v11 * tx;
    return top * (1.0f - ty) + bot * ty;
}

__global__ __launch_bounds__(256) void fuse_kernel(float* __restrict__ out,
                                                   const float* __restrict__ y2,
                                                   const float* __restrict__ y4,
                                                   const float* __restrict__ sw) {
    int idx = blockIdx.x * 256 + threadIdx.x;
    int p = idx & 4095;
    int bc = idx >> 12;
    int oy = p >> 6, ox = p & 63;
    float w0, w1, w2; scale_wts(sw, w0, w1, w2);
    float v2 = bilerp(y2 + bc * 1024, 32, oy, ox, 0.5f);
    float v4 = bilerp(y4 + bc * 256, 16, oy, ox, 0.25f);
    out[idx] = out[idx] + w1 * v2 + w2 * v4;
}

extern "C" void kernel_launch(void* const* d_in, const int* in_sizes, int n_in,
                              void* d_out, int out_size, void* d_ws, size_t ws_size,
                              hipStream_t stream) {
    const float* x     = (const float*)d_in[0];
    const float* gn_w  = (const float*)d_in[1];
    const float* gn_b  = (const float*)d_in[2];
    const float* qw    = (const float*)d_in[3];
    const float* qb    = (const float*)d_in[4];
    const float* kw    = (const float*)d_in[5];
    const float* kb    = (const float*)d_in[6];
    const float* vw    = (const float*)d_in[7];
    const float* vb    = (const float*)d_in[8];
    const float* ow    = (const float*)d_in[9];
    const float* ob    = (const float*)d_in[10];
    const float* gamma = (const float*)d_in[11];
    const float* sw    = (const float*)d_in[12];
    float* out = (float*)d_out;

    float* ws    = (float*)d_ws;
    float* xs2   = ws;                         // 524288
    float* xs4   = xs2 + 524288;               // 131072
    float* y2    = xs4 + 131072;               // 524288
    float* y4    = y2 + 524288;                // 131072
    float* part  = y4 + 131072;                // 3072
    float* pacc  = part + 3072;                // PATOT = 2752512
    float* pml   = pacc + PATOT;               // PMTOT = 172032
    ushort_t* qbf = (ushort_t*)(pml + PMTOT);  // QTOT ushorts each
    ushort_t* kbf = qbf + QTOT;
    ushort_t* vbf = kbf + QTOT;

    pool_stats_kernel<<<1536, 256, 0, stream>>>(x, xs2, xs4, part);
    qkv_all_kernel<<<1008, 256, 0, stream>>>(x, xs2, xs4, part, gn_w, gn_b,
                                             qw, qb, kw, kb, vw, vb, qbf, kbf, vbf);
    attn_all_kernel<<<1344, 256, 0, stream>>>(qbf, kbf, vbf, pacc, pml);
    comb_oy_all_kernel<<<672, 256, 0, stream>>>(pacc, pml, ow, ob, gamma,
                                                x, xs2, xs4, out, y2, y4, sw);
    fuse_kernel<<<8192, 256, 0, stream>>>(out, y2, y4, sw);
}